// Round 8
// baseline (98.149 us; speedup 1.0000x reference)
//
#include <hip/hip_runtime.h>

// VMD (Variational Mode Decomposition) for x: (16, 8192, 4) f32.
// B=16, C=4, T=8192, T2=16384, K=4, ALPHA=2000, TAU=0, 20 iterations.
// TAU=0 => lam == 0. Negative half stays 0 => iterate on 8192 positive bins.
//
// R24: ATTRIBUTION ROUND. The forward kernel is split into two dispatches
// so rocprof reports each phase's duration directly (my FFT-vs-iteration
// budget is unverified and decides the next structural move):
//   vmd_fft:  redundant per-channel real-FFT + untangle; spills each
//             block's 2048-bin quarter R to ws_R (4 MB, coalesced float2).
//   vmd_iter: loads R, runs the 20 VMD iterations with the R18 sync
//             skeleton VERBATIM (hw barriers + wave0-only fold/publish/
//             sc1-sentinel spin; it=19 tail skip); writes u_hat f16 + omega.
//   vmd_inverse: R22 inverse verbatim.
// Cross-dispatch handoffs are plain stores/loads (same-stream kernel
// boundaries give visibility -- proven by R18/R22's ws_u handoff).
// Math is bit-identical to R22/R23. Cost: +1 launch gap + 4 MB round trip.
// Decision rule: fft >= 15us -> cooperative four-step FFT next;
// fft <= 9us -> iteration sync floor confirmed, FFT-sharing is dead.

#define HALF      8192
#define NH        8192        // half-size FFT length
#define NTHREADS  1024
#define KMODES    4
#define NITERS    20
#define ALPHA_F   2000.0f
#define SQH       0.70710678118654752440f
#define SENTINEL  0xFFFFFFFFu

typedef __fp16 half2_t __attribute__((ext_vector_type(2)));
typedef float  v2f     __attribute__((ext_vector_type(2)));

__device__ __forceinline__ unsigned bitrev13(unsigned x) { return __brev(x) >> 19; }
__device__ __forceinline__ int pidx(int i) { return i + (i >> 4); }   // LDS pad

__device__ __forceinline__ unsigned pack_h2(float a, float b) {
    half2_t h = __builtin_amdgcn_cvt_pkrtz(a, b);   // v_cvt_pkrtz_f16_f32
    return __builtin_bit_cast(unsigned, h);
}
__device__ __forceinline__ v2f unpack_h2(unsigned u) {
    half2_t h = __builtin_bit_cast(half2_t, u);
    v2f r; r.x = (float)h.x; r.y = (float)h.y; return r;
}

template <int CTRL>
__device__ __forceinline__ float dpp_add_step(float v) {
    int r = __builtin_amdgcn_update_dpp(0, __float_as_int(v), CTRL, 0xf, 0xf, true);
    return v + __int_as_float(r);
}
// Full-wave (64-lane) sum; result valid in lane 63.
__device__ __forceinline__ float wave64_sum(float v) {
    v = dpp_add_step<0x111>(v);   // row_shr:1
    v = dpp_add_step<0x112>(v);   // row_shr:2
    v = dpp_add_step<0x114>(v);   // row_shr:4
    v = dpp_add_step<0x118>(v);   // row_shr:8
    v = dpp_add_step<0x142>(v);   // row_bcast:15
    v = dpp_add_step<0x143>(v);   // row_bcast:31 -> lane63 = wave sum
    return v;
}

__device__ __forceinline__ float2 cmul(float2 a, float wr, float wi) {
    return make_float2(a.x * wr - a.y * wi, a.x * wi + a.y * wr);
}
__device__ __forceinline__ float2 cadd(float2 a, float2 b) {
    return make_float2(a.x + b.x, a.y + b.y);
}
__device__ __forceinline__ float2 csub(float2 a, float2 b) {
    return make_float2(a.x - b.x, a.y - b.y);
}

// One radix-8 pass = three fused radix-2 DIF stages.
template <bool INV>
__device__ __forceinline__ void fft_pass8(float2* A, int tid, int t) {
    const int   log2Q = 10 - 3 * t;
    const int   Q     = 1 << log2Q;
    const float invL  = (float)(1 << (3 * t)) * (1.0f / 8192.0f);  // 1/(8Q)
    const int j    = tid & (Q - 1);
    const int base = ((tid >> log2Q) << (log2Q + 3)) + j;

    float2 x[8];
    #pragma unroll
    for (int m = 0; m < 8; ++m) x[m] = A[pidx(base + m * Q)];

    float rev = (float)j * invL;
    float w1r = __builtin_amdgcn_cosf(rev);
    float w1i = INV ?  __builtin_amdgcn_sinf(rev)
                    : -__builtin_amdgcn_sinf(rev);
    float w2r = w1r * w1r - w1i * w1i, w2i = 2.0f * w1r * w1i;
    float w4r = w2r * w2r - w2i * w2i, w4i = 2.0f * w2r * w2i;
    float wsr, wsi;
    if (INV) { wsr = SQH * (w1r - w1i); wsi = SQH * (w1r + w1i); }
    else     { wsr = SQH * (w1r + w1i); wsi = SQH * (w1i - w1r); }
    float w1tr = INV ? -w1i : w1i,  w1ti = INV ? w1r : -w1r;
    float wstr = INV ? -wsi : wsi,  wsti = INV ? wsr : -wsr;
    float w2tr = INV ? -w2i : w2i,  w2ti = INV ? w2r : -w2r;

    float2 y0 = cadd(x[0], x[4]), y1 = cadd(x[1], x[5]);
    float2 y2 = cadd(x[2], x[6]), y3 = cadd(x[3], x[7]);
    float2 y4 = cmul(csub(x[0], x[4]), w1r, w1i);
    float2 y5 = cmul(csub(x[1], x[5]), wsr, wsi);
    float2 y6 = cmul(csub(x[2], x[6]), w1tr, w1ti);
    float2 y7 = cmul(csub(x[3], x[7]), wstr, wsti);

    float2 z0 = cadd(y0, y2), z2 = cmul(csub(y0, y2), w2r, w2i);
    float2 z1 = cadd(y1, y3), z3 = cmul(csub(y1, y3), w2tr, w2ti);
    float2 z4 = cadd(y4, y6), z6 = cmul(csub(y4, y6), w2r, w2i);
    float2 z5 = cadd(y5, y7), z7 = cmul(csub(y5, y7), w2tr, w2ti);

    A[pidx(base + 0 * Q)] = cadd(z0, z1);
    A[pidx(base + 1 * Q)] = cmul(csub(z0, z1), w4r, w4i);
    A[pidx(base + 2 * Q)] = cadd(z2, z3);
    A[pidx(base + 3 * Q)] = cmul(csub(z2, z3), w4r, w4i);
    A[pidx(base + 4 * Q)] = cadd(z4, z5);
    A[pidx(base + 5 * Q)] = cmul(csub(z4, z5), w4r, w4i);
    A[pidx(base + 6 * Q)] = cadd(z6, z7);
    A[pidx(base + 7 * Q)] = cmul(csub(z6, z7), w4r, w4i);
}

// Final radix-2 stage (half=1): pairs (2t, 2t+1), twiddle = 1.
__device__ __forceinline__ void fft_last2(float2* A, int tid) {
    #pragma unroll
    for (int u = 0; u < 4; ++u) {
        int t  = tid + u * NTHREADS;
        int i0 = 2 * t, i1 = 2 * t + 1;
        float2 a = A[pidx(i0)], b = A[pidx(i1)];
        A[pidx(i0)] = make_float2(a.x + b.x, a.y + b.y);
        A[pidx(i1)] = make_float2(a.x - b.x, a.y - b.y);
    }
}

// time-domain mirror extension: f[i], i in [0,16384)
__device__ __forceinline__ int mirror_t(int i) {
    if (i < 4096)       return 4095 - i;
    else if (i < 12288) return i - 4096;
    else                return 20479 - i;
}

// ---------------------------------------------------------------------------
// Kernel A: per-channel real-FFT (redundant across the channel's 4 blocks)
// + untangle; spills this block's 2048-bin quarter to ws_R.
// Grid 256: ch = bid & 63, q = bid >> 6.
// ---------------------------------------------------------------------------
__global__ __launch_bounds__(NTHREADS) void vmd_fft(
    const float* __restrict__ x, float2* __restrict__ ws_R)
{
    __shared__ float2 A[NH + (NH >> 4)];   // padded, ~68 KB
    const int tid = threadIdx.x;
    const int bid = blockIdx.x;
    const int ch  = bid & 63;            // b*4 + c
    const int q   = bid >> 6;            // quarter index 0..3
    const int b   = ch >> 2, c = ch & 3;
    const float* xb = x + (size_t)b * 8192 * 4 + c;   // x[b, t, c], stride 4

    // z[m] = f[2m] + i f[2m+1]
    for (int m = tid; m < NH; m += NTHREADS) {
        float re = xb[(size_t)mirror_t(2 * m) * 4];
        float im = xb[(size_t)mirror_t(2 * m + 1) * 4];
        A[pidx(m)] = make_float2(re, im);
    }
    __syncthreads();

    // 8192-pt forward FFT: 4 radix-8 passes + 1 radix-2 stage; bit-reversed out.
    for (int t = 0; t < 4; ++t) {
        fft_pass8<false>(A, tid, t);
        __syncthreads();
    }
    fft_last2(A, tid);
    __syncthreads();

    // Untangle our quarter: F[j] = E[j] + w*O[j], w = e^{-2*pi*i*j/16384},
    // j = q*2048 + tid + u*1024, u in {0,1}. Spill to ws_R (coalesced).
    #pragma unroll
    for (int u = 0; u < 2; ++u) {
        int j  = (q << 11) + tid + u * NTHREADS;
        float2 z1 = A[pidx((int)bitrev13((unsigned)j))];
        float2 z2 = A[pidx((int)bitrev13((unsigned)((NH - j) & (NH - 1))))];
        float ex = 0.5f * (z1.x + z2.x);
        float ey = 0.5f * (z1.y - z2.y);
        float dx = 0.5f * (z1.x - z2.x);
        float dy = 0.5f * (z1.y + z2.y);
        // O = (dy, -dx)
        float rev = (float)j * (1.0f / 16384.0f);
        float wr = __builtin_amdgcn_cosf(rev);
        float wi = -__builtin_amdgcn_sinf(rev);
        ws_R[(size_t)bid * 2048 + tid + u * NTHREADS] =
            make_float2(ex + wr * dy + wi * dx, ey + wi * dy - wr * dx);
    }
}

// ---------------------------------------------------------------------------
// Kernel B: 20 VMD iterations on a 2048-bin quarter per block (R18 sync
// skeleton verbatim; it=19 tail skip). Grid 256: ch = bid & 63, q = bid>>6.
// Reads ws_R (plain, cross-dispatch), writes u_hat f16 + omega (plain).
// ---------------------------------------------------------------------------
__global__ __launch_bounds__(NTHREADS) void vmd_iter(
    const float2* __restrict__ ws_R, unsigned* __restrict__ ws_u,
    float* __restrict__ ws_omega, unsigned* __restrict__ ws_part)
{
    __shared__ float red[2 * 144];       // two 144-float slabs (parity dbuf)
    const int tid = threadIdx.x;
    const int bid = blockIdx.x;
    const int ch  = bid & 63;
    const int q   = bid >> 6;

    v2f R[2];
    #pragma unroll
    for (int u = 0; u < 2; ++u) {
        float2 r = ws_R[(size_t)bid * 2048 + tid + u * NTHREADS];
        R[u].x = r.x; R[u].y = r.y;
    }

    v2f Up[KMODES][2];   // U_k in f32 registers (re, im)
    #pragma unroll
    for (int u = 0; u < 2; ++u)
        #pragma unroll
        for (int k = 0; k < KMODES; ++k) { Up[k][u].x = 0.f; Up[k][u].y = 0.f; }

    const float f0 = (float)((q << 11) + tid) * (1.0f / 16384.0f);
    float omg[KMODES] = {0.0f, 0.125f, 0.25f, 0.375f};  // 0.5*k/K

    const int lane = tid & 63, wid = tid >> 6;

    for (int it = 0; it < NITERS; ++it) {
        v2f nd[KMODES];       // (num, den) packed per mode
        #pragma unroll
        for (int k = 0; k < KMODES; ++k) { nd[k].x = 0.f; nd[k].y = 0.f; }
        #pragma unroll
        for (int u = 0; u < 2; ++u) {
            const float fru = f0 + (float)u * 0.0625f;
            v2f fv; fv.x = fru; fv.y = 1.0f;
            #pragma unroll
            for (int k = 0; k < KMODES; ++k) {
                float d   = fru - omg[k];
                float dnm = fmaf(ALPHA_F * d, d, 1.0f);
                float rcp = __builtin_amdgcn_rcpf(dnm);
                v2f uo  = Up[k][u];
                v2f nm  = R[u] + uo;          // v_pk_add_f32
                v2f un  = nm * rcp;           // v_pk_mul_f32 (splat)
                R[u]    = nm - un;            // v_pk_add_f32
                Up[k][u] = un;
                float p = fmaf(un.x, un.x, un.y * un.y);
                nd[k]   = fv * p + nd[k];     // v_pk_fma_f32
            }
        }
        // Stage 1: DPP wave sums, lane63 writes 8 partials for this wave.
        float num[KMODES], den[KMODES];
        #pragma unroll
        for (int m = 0; m < KMODES; ++m) {
            num[m] = wave64_sum(nd[m].x);
            den[m] = wave64_sum(nd[m].y);
        }
        float* redb = red + (it & 1) * 144;   // [0..127] wave partials, [128..135] totals
        if (lane == 63) {
            float4* r4 = (float4*)&redb[wid * 8];
            r4[0] = make_float4(num[0], num[1], num[2], num[3]);
            r4[1] = make_float4(den[0], den[1], den[2], den[3]);
        }
        __syncthreads();   // barrier #1: wave partials visible in LDS
        const bool last_it = (it == NITERS - 1);
        unsigned* pp = ws_part + (((size_t)it * 64 + ch) << 5);
        if (wid == 0) {
            // Fold 16x8 wave partials -> block partial (lane l holds class l&7).
            float v = redb[lane] + redb[lane + 64];
            v += __int_as_float(__builtin_amdgcn_ds_swizzle(__float_as_int(v), 0x201F)); // xor 8
            v += __int_as_float(__builtin_amdgcn_ds_swizzle(__float_as_int(v), 0x401F)); // xor 16
            v += __int_as_float(__builtin_amdgcn_ds_bpermute((lane ^ 32) << 2,
                                                             __float_as_int(v)));
            // Relaxed-only publish: payload travels in the atomic word itself.
            if (lane < 8)
                __hip_atomic_store(pp + (q << 3) + lane, __float_as_uint(v),
                                   __ATOMIC_RELAXED, __HIP_MEMORY_SCOPE_AGENT);
            // Gather (skip at it=19 unless q==0: final reduce feeds only ws_omega).
            if (!last_it || q == 0) {
                float t = 0.0f;
                if (lane < 32) {
                    unsigned w;
                    for (;;) {
                        w = __hip_atomic_load(pp + lane, __ATOMIC_RELAXED,
                                              __HIP_MEMORY_SCOPE_AGENT);
                        if (w != SENTINEL) break;
                        __builtin_amdgcn_s_sleep(1);
                    }
                    t = __uint_as_float(w);
                }
                // Fold over the 4 quarters (lanes xor 8 / xor 16 within 0-31).
                t += __int_as_float(__builtin_amdgcn_ds_swizzle(__float_as_int(t), 0x201F)); // xor 8
                t += __int_as_float(__builtin_amdgcn_ds_swizzle(__float_as_int(t), 0x401F)); // xor 16
                if (!last_it) {
                    if (lane < 8) redb[128 + lane] = t;   // totals -> LDS broadcast
                } else {
                    // it=19, q==0: omg needed only for the ws_omega write (tid<4).
                    #pragma unroll
                    for (int m = 0; m < KMODES; ++m) {
                        float nm_ = __int_as_float(__builtin_amdgcn_readlane(__float_as_int(t), m));
                        float dn_ = __int_as_float(__builtin_amdgcn_readlane(__float_as_int(t), m + 4));
                        omg[m] = nm_ * __builtin_amdgcn_rcpf(dn_);
                    }
                }
            }
        }
        if (!last_it) {
            __syncthreads();   // barrier #2: totals visible to all waves
            #pragma unroll
            for (int m = 0; m < KMODES; ++m) {
                float nm_ = redb[128 + m];
                float dn_ = redb[128 + m + 4];
                omg[m] = nm_ * __builtin_amdgcn_rcpf(dn_);
            }
        }
        // it=19: no barrier #2 -- 15 waves fall through to the u_hat stores
        // while q==0's wave0 finishes its gather.
    }

    // Write final positive-half u_hat quarter (packed f16) and omega.
    #pragma unroll
    for (int k = 0; k < KMODES; ++k) {
        unsigned* dst = ws_u + (size_t)(ch * KMODES + k) * HALF + (q << 11);
        #pragma unroll
        for (int u = 0; u < 2; ++u)
            dst[tid + u * NTHREADS] = pack_h2(Up[k][u].x, Up[k][u].y);
    }
    if (q == 0 && tid < KMODES) ws_omega[ch * KMODES + tid] = omg[tid];
}

// ---------------------------------------------------------------------------
// Kernel C: per (channel,mode) half-size real iFFT -> out[b,k,t,c] scatter.
// R22 inverse verbatim (R13 write-merge remap; block 0 computes omega_b).
// ---------------------------------------------------------------------------
__global__ __launch_bounds__(NTHREADS) void vmd_inverse(
    const unsigned* __restrict__ ws_u, const float* __restrict__ ws_omega,
    float* __restrict__ out)
{
    __shared__ float2 A[NH + (NH >> 4)];
    const int tid = threadIdx.x;
    const int bid = blockIdx.x;
    const int g   = bid & 63;               // (b,k) group
    const int c   = bid >> 6;
    const int b   = g >> 2, k = g & 3;
    const int ch  = b * 4 + c;
    const unsigned* pos = ws_u + (size_t)(ch * KMODES + k) * HALF;

    if (bid == 0 && tid < 64) {
        int bb = tid >> 2, kk = tid & 3;
        float s = 0.f;
        #pragma unroll
        for (int cc = 0; cc < 4; ++cc) s += ws_omega[(bb * 4 + cc) * 4 + kk];
        out[2097152 + tid] = 0.25f * s;
    }

    for (int j = tid; j < NH; j += NTHREADS) {
        v2f pj = unpack_h2(pos[j]);
        v2f ph = unpack_h2(pos[j ? (HALF - j) : (HALF - 1)]);
        float gjx = pj.x, gjy = (j == 0) ? -pj.y : pj.y;  // G[0] = conj(p[0])
        float ghx = ph.x, ghy = -ph.y;                     // conj
        float ex = 0.5f * (gjx + ghx), ey = 0.5f * (gjy + ghy);
        float dx = 0.5f * (gjx - ghx), dy = 0.5f * (gjy - ghy);
        float rev = (float)j * (1.0f / 16384.0f);
        float wr = __builtin_amdgcn_cosf(rev);
        float wi = __builtin_amdgcn_sinf(rev);    // e^{+2*pi*i*rev}
        float ox = dx * wr - dy * wi;
        float oy = dx * wi + dy * wr;
        A[pidx(j)] = make_float2(ex - oy, ey + ox);   // Z = E + i*O
    }
    __syncthreads();

    // 8192-pt inverse FFT: 4 radix-8 passes + 1 radix-2 stage; bit-reversed out.
    for (int t = 0; t < 4; ++t) {
        fft_pass8<true>(A, tid, t);
        __syncthreads();
    }
    fft_last2(A, tid);
    __syncthreads();

    // Keep n in [4096,12288): m in [2048,6144). x[2m]=Re z, x[2m+1]=Im z.
    float* outp = out + (size_t)(b * 4 + k) * 8192 * 4 + c;
    for (int m = 2048 + tid; m < 6144; m += NTHREADS) {
        float2 z = A[pidx((int)bitrev13((unsigned)m))];
        int t0 = 2 * m - 4096;
        outp[(size_t)t0 * 4]       = z.x * (1.0f / 8192.0f);
        outp[(size_t)(t0 + 1) * 4] = z.y * (1.0f / 8192.0f);
    }
}

extern "C" void kernel_launch(void* const* d_in, const int* in_sizes, int n_in,
                              void* d_out, int out_size, void* d_ws, size_t ws_size,
                              hipStream_t stream)
{
    (void)in_sizes; (void)n_in; (void)out_size; (void)ws_size;
    const float* x = (const float*)d_in[0];
    float* out = (float*)d_out;

    // ws layout:
    //   [0, 8 MB)            u_hat packed f16: 64 ch * 4 modes * 8192 u32
    //   [8 MB, +1 KB)        omega: 64 ch * 4 modes f32
    //   [+1 KB, +160 KB)     cross-block partials: NITERS * 64 ch * 32 u32
    //   [..., +4 MB]         ws_R: 256 blocks * 2048 float2 (spilled spectrum)
    unsigned* ws_u     = (unsigned*)d_ws;
    float*    ws_omega = (float*)((char*)d_ws + (size_t)64 * 4 * HALF * 4);
    unsigned* ws_part  = (unsigned*)((char*)d_ws + (size_t)64 * 4 * HALF * 4 + 1024);
    float2*   ws_R     = (float2*)((char*)d_ws + (size_t)64 * 4 * HALF * 4 + 1024
                                   + (size_t)NITERS * 64 * 32 * 4);

    hipMemsetAsync(ws_part, 0xFF, (size_t)NITERS * 64 * 32 * 4, stream);
    vmd_fft<<<256, NTHREADS, 0, stream>>>(x, ws_R);
    vmd_iter<<<256, NTHREADS, 0, stream>>>(ws_R, ws_u, ws_omega, ws_part);
    vmd_inverse<<<256, NTHREADS, 0, stream>>>(ws_u, ws_omega, out);
}

// Round 9
// 83.463 us; speedup vs baseline: 1.1760x; 1.1760x over previous
//
#include <hip/hip_runtime.h>

// VMD (Variational Mode Decomposition) for x: (16, 8192, 4) f32.
// B=16, C=4, T=8192, T2=16384, K=4, ALPHA=2000, TAU=0, 20 iterations.
// TAU=0 => lam == 0. Negative half stays 0 => iterate on 8192 positive bins.
//
// R25 = R23 fused structure + XCD-local sync probe with placement coverage:
// R24 attribution: iter = 61.9us (3.1/iter, sync-dominated), fft ~14,
// inverse ~14. R21's L2 fast path (mates 64-apart) never engaged; 64-apart
// is same-XCD under block-RR(%8) and SE-RR policies, so the surviving
// hypothesis is FILL-FIRST dispatch (bid/32 = XCD). This round: phase-1
// mates are 8-APART (bid = a*32 + 8q + r -> ch = a*8+r, quarter q) --
// same-XCD under fill-first AND %8-RR. Dual-path publish (plain store ->
// local L2; relaxed-agent sc1 -> IC) with FAST-THEN-SLOW POLL EVERY LOOP
// (R21's 1/8 slow decimation was the bug). Words are write-once with
// payload-in-word sentinels: any non-sentinel read is a genuine payload
// under ANY placement -> correct either way; worst case ~R18+0.2us/iter.
// Phase 2 (inverse) and its sc1 flag handoff unchanged from R23.

#define HALF      8192
#define NH        8192        // half-size FFT length
#define NTHREADS  1024
#define KMODES    4
#define NITERS    20
#define ALPHA_F   2000.0f
#define SQH       0.70710678118654752440f
#define SENTINEL  0xFFFFFFFFu

typedef __fp16 half2_t __attribute__((ext_vector_type(2)));
typedef float  v2f     __attribute__((ext_vector_type(2)));

__device__ __forceinline__ unsigned bitrev13(unsigned x) { return __brev(x) >> 19; }
__device__ __forceinline__ int pidx(int i) { return i + (i >> 4); }   // LDS pad

__device__ __forceinline__ unsigned pack_h2(float a, float b) {
    half2_t h = __builtin_amdgcn_cvt_pkrtz(a, b);   // v_cvt_pkrtz_f16_f32
    return __builtin_bit_cast(unsigned, h);
}
__device__ __forceinline__ v2f unpack_h2(unsigned u) {
    half2_t h = __builtin_bit_cast(half2_t, u);
    v2f r; r.x = (float)h.x; r.y = (float)h.y; return r;
}

__device__ __forceinline__ unsigned ic_load(const unsigned* p) {
    return __hip_atomic_load(p, __ATOMIC_RELAXED, __HIP_MEMORY_SCOPE_AGENT);
}
__device__ __forceinline__ void ic_store(unsigned* p, unsigned v) {
    __hip_atomic_store(p, v, __ATOMIC_RELAXED, __HIP_MEMORY_SCOPE_AGENT);
}
// Plain global store: lands in the XCD's L2 (L1 is write-through).
__device__ __forceinline__ void store_plain(unsigned* p, unsigned v) {
    asm volatile("global_store_dword %0, %1, off" :: "v"(p), "v"(v) : "memory");
}
// L1-bypass load: reads this XCD's L2 (sc0).
__device__ __forceinline__ unsigned load_sc0(const unsigned* p) {
    unsigned r;
    asm volatile("global_load_dword %0, %1, off sc0\n\t"
                 "s_waitcnt vmcnt(0)"
                 : "=v"(r) : "v"(p) : "memory");
    return r;
}

template <int CTRL>
__device__ __forceinline__ float dpp_add_step(float v) {
    int r = __builtin_amdgcn_update_dpp(0, __float_as_int(v), CTRL, 0xf, 0xf, true);
    return v + __int_as_float(r);
}
// Full-wave (64-lane) sum; result valid in lane 63.
__device__ __forceinline__ float wave64_sum(float v) {
    v = dpp_add_step<0x111>(v);   // row_shr:1
    v = dpp_add_step<0x112>(v);   // row_shr:2
    v = dpp_add_step<0x114>(v);   // row_shr:4
    v = dpp_add_step<0x118>(v);   // row_shr:8
    v = dpp_add_step<0x142>(v);   // row_bcast:15
    v = dpp_add_step<0x143>(v);   // row_bcast:31 -> lane63 = wave sum
    return v;
}

__device__ __forceinline__ float2 cmul(float2 a, float wr, float wi) {
    return make_float2(a.x * wr - a.y * wi, a.x * wi + a.y * wr);
}
__device__ __forceinline__ float2 cadd(float2 a, float2 b) {
    return make_float2(a.x + b.x, a.y + b.y);
}
__device__ __forceinline__ float2 csub(float2 a, float2 b) {
    return make_float2(a.x - b.x, a.y - b.y);
}

// One radix-8 pass = three fused radix-2 DIF stages.
template <bool INV>
__device__ __forceinline__ void fft_pass8(float2* A, int tid, int t) {
    const int   log2Q = 10 - 3 * t;
    const int   Q     = 1 << log2Q;
    const float invL  = (float)(1 << (3 * t)) * (1.0f / 8192.0f);  // 1/(8Q)
    const int j    = tid & (Q - 1);
    const int base = ((tid >> log2Q) << (log2Q + 3)) + j;

    float2 x[8];
    #pragma unroll
    for (int m = 0; m < 8; ++m) x[m] = A[pidx(base + m * Q)];

    float rev = (float)j * invL;
    float w1r = __builtin_amdgcn_cosf(rev);
    float w1i = INV ?  __builtin_amdgcn_sinf(rev)
                    : -__builtin_amdgcn_sinf(rev);
    float w2r = w1r * w1r - w1i * w1i, w2i = 2.0f * w1r * w1i;
    float w4r = w2r * w2r - w2i * w2i, w4i = 2.0f * w2r * w2i;
    float wsr, wsi;
    if (INV) { wsr = SQH * (w1r - w1i); wsi = SQH * (w1r + w1i); }
    else     { wsr = SQH * (w1r + w1i); wsi = SQH * (w1i - w1r); }
    float w1tr = INV ? -w1i : w1i,  w1ti = INV ? w1r : -w1r;
    float wstr = INV ? -wsi : wsi,  wsti = INV ? wsr : -wsr;
    float w2tr = INV ? -w2i : w2i,  w2ti = INV ? w2r : -w2r;

    float2 y0 = cadd(x[0], x[4]), y1 = cadd(x[1], x[5]);
    float2 y2 = cadd(x[2], x[6]), y3 = cadd(x[3], x[7]);
    float2 y4 = cmul(csub(x[0], x[4]), w1r, w1i);
    float2 y5 = cmul(csub(x[1], x[5]), wsr, wsi);
    float2 y6 = cmul(csub(x[2], x[6]), w1tr, w1ti);
    float2 y7 = cmul(csub(x[3], x[7]), wstr, wsti);

    float2 z0 = cadd(y0, y2), z2 = cmul(csub(y0, y2), w2r, w2i);
    float2 z1 = cadd(y1, y3), z3 = cmul(csub(y1, y3), w2tr, w2ti);
    float2 z4 = cadd(y4, y6), z6 = cmul(csub(y4, y6), w2r, w2i);
    float2 z5 = cadd(y5, y7), z7 = cmul(csub(y5, y7), w2tr, w2ti);

    A[pidx(base + 0 * Q)] = cadd(z0, z1);
    A[pidx(base + 1 * Q)] = cmul(csub(z0, z1), w4r, w4i);
    A[pidx(base + 2 * Q)] = cadd(z2, z3);
    A[pidx(base + 3 * Q)] = cmul(csub(z2, z3), w4r, w4i);
    A[pidx(base + 4 * Q)] = cadd(z4, z5);
    A[pidx(base + 5 * Q)] = cmul(csub(z4, z5), w4r, w4i);
    A[pidx(base + 6 * Q)] = cadd(z6, z7);
    A[pidx(base + 7 * Q)] = cmul(csub(z6, z7), w4r, w4i);
}

// Final radix-2 stage (half=1): pairs (2t, 2t+1), twiddle = 1.
__device__ __forceinline__ void fft_last2(float2* A, int tid) {
    #pragma unroll
    for (int u = 0; u < 4; ++u) {
        int t  = tid + u * NTHREADS;
        int i0 = 2 * t, i1 = 2 * t + 1;
        float2 a = A[pidx(i0)], b = A[pidx(i1)];
        A[pidx(i0)] = make_float2(a.x + b.x, a.y + b.y);
        A[pidx(i1)] = make_float2(a.x - b.x, a.y - b.y);
    }
}

// time-domain mirror extension: f[i], i in [0,16384)
__device__ __forceinline__ int mirror_t(int i) {
    if (i < 4096)       return 4095 - i;
    else if (i < 12288) return i - 4096;
    else                return 20479 - i;
}

// ---------------------------------------------------------------------------
// Fused kernel. Grid 256, 1024 threads.
// Phase 1 (forward): bid = a*32 + 8q + r -> ch = a*8 + r, quarter q.
// Channel-mates are 8-apart (same XCD under fill-first AND %8-RR dispatch).
// Redundant per-channel real-FFT + 20 VMD iterations on a 2048-bin quarter;
// R18 skeleton with dual-path publish + fast-then-slow poll.
// Phase 2 (inverse): g = bid & 63 -> (b,k), c = bid >> 6 (R13 write-merge
// mapping); sc1 flag handoff; batched sc1 Z staging; iFFT; scatter.
// ---------------------------------------------------------------------------
__global__ __launch_bounds__(NTHREADS) void vmd_fused(
    const float* __restrict__ x, unsigned* __restrict__ ws_u,
    unsigned* __restrict__ ws_omega, unsigned* __restrict__ ws_partf,
    unsigned* __restrict__ ws_parts, unsigned* __restrict__ ws_udone,
    float* __restrict__ out)
{
    __shared__ float2 A[NH + (NH >> 4)];   // padded, ~68 KB
    const int tid = threadIdx.x;
    const int bid = blockIdx.x;
    const int r8  = bid & 7;             // XCD residue (both policies)
    const int q   = (bid >> 3) & 3;      // quarter index 0..3
    const int a8  = bid >> 5;
    const int ch  = a8 * 8 + r8;         // b*4 + c
    const int b   = ch >> 2, c = ch & 3;
    const float* xb = x + (size_t)b * 8192 * 4 + c;   // x[b, t, c], stride 4

    // ---------------- Phase 1: forward FFT + iterations ----------------
    // z[m] = f[2m] + i f[2m+1]
    for (int m = tid; m < NH; m += NTHREADS) {
        float re = xb[(size_t)mirror_t(2 * m) * 4];
        float im = xb[(size_t)mirror_t(2 * m + 1) * 4];
        A[pidx(m)] = make_float2(re, im);
    }
    __syncthreads();

    // 8192-pt forward FFT: 4 radix-8 passes + 1 radix-2 stage; bit-reversed out.
    for (int t = 0; t < 4; ++t) {
        fft_pass8<false>(A, tid, t);
        __syncthreads();
    }
    fft_last2(A, tid);
    __syncthreads();

    // Untangle our quarter: F[j] = E[j] + w*O[j], w = e^{-2*pi*i*j/16384},
    // j = q*2048 + tid + u*1024, u in {0,1}.
    v2f R[2];
    #pragma unroll
    for (int u = 0; u < 2; ++u) {
        int j  = (q << 11) + tid + u * NTHREADS;
        float2 z1 = A[pidx((int)bitrev13((unsigned)j))];
        float2 z2 = A[pidx((int)bitrev13((unsigned)((NH - j) & (NH - 1))))];
        float ex = 0.5f * (z1.x + z2.x);
        float ey = 0.5f * (z1.y - z2.y);
        float dx = 0.5f * (z1.x - z2.x);
        float dy = 0.5f * (z1.y + z2.y);
        // O = (dy, -dx)
        float rev = (float)j * (1.0f / 16384.0f);
        float wr = __builtin_amdgcn_cosf(rev);
        float wi = -__builtin_amdgcn_sinf(rev);
        R[u].x = ex + wr * dy + wi * dx;
        R[u].y = ey + wi * dy - wr * dx;
    }
    __syncthreads();   // LDS now reusable as reduction scratch

    v2f Up[KMODES][2];   // U_k in f32 registers (re, im)
    #pragma unroll
    for (int u = 0; u < 2; ++u)
        #pragma unroll
        for (int k = 0; k < KMODES; ++k) { Up[k][u].x = 0.f; Up[k][u].y = 0.f; }

    const float f0 = (float)((q << 11) + tid) * (1.0f / 16384.0f);
    float omg[KMODES] = {0.0f, 0.125f, 0.25f, 0.375f};  // 0.5*k/K

    float* red = (float*)A;   // two 144-float slabs (double-buffered by parity)
    const int lane = tid & 63, wid = tid >> 6;

    for (int it = 0; it < NITERS; ++it) {
        v2f nd[KMODES];       // (num, den) packed per mode
        #pragma unroll
        for (int k = 0; k < KMODES; ++k) { nd[k].x = 0.f; nd[k].y = 0.f; }
        #pragma unroll
        for (int u = 0; u < 2; ++u) {
            const float fru = f0 + (float)u * 0.0625f;
            v2f fv; fv.x = fru; fv.y = 1.0f;
            #pragma unroll
            for (int k = 0; k < KMODES; ++k) {
                float d   = fru - omg[k];
                float dnm = fmaf(ALPHA_F * d, d, 1.0f);
                float rcp = __builtin_amdgcn_rcpf(dnm);
                v2f uo  = Up[k][u];
                v2f nm  = R[u] + uo;          // v_pk_add_f32
                v2f un  = nm * rcp;           // v_pk_mul_f32 (splat)
                R[u]    = nm - un;            // v_pk_add_f32
                Up[k][u] = un;
                float p = fmaf(un.x, un.x, un.y * un.y);
                nd[k]   = fv * p + nd[k];     // v_pk_fma_f32
            }
        }
        // Stage 1: DPP wave sums, lane63 writes 8 partials for this wave.
        float num[KMODES], den[KMODES];
        #pragma unroll
        for (int m = 0; m < KMODES; ++m) {
            num[m] = wave64_sum(nd[m].x);
            den[m] = wave64_sum(nd[m].y);
        }
        float* redb = red + (it & 1) * 144;   // [0..127] wave partials, [128..135] totals
        if (lane == 63) {
            float4* r4 = (float4*)&redb[wid * 8];
            r4[0] = make_float4(num[0], num[1], num[2], num[3]);
            r4[1] = make_float4(den[0], den[1], den[2], den[3]);
        }
        __syncthreads();   // barrier #1: wave partials visible in LDS
        const bool last_it = (it == NITERS - 1);
        unsigned* ppf = ws_partf + (((size_t)it * 64 + ch) << 5);
        unsigned* pps = ws_parts + (((size_t)it * 64 + ch) << 5);
        if (wid == 0) {
            // Fold 16x8 wave partials -> block partial (lane l holds class l&7).
            float v = redb[lane] + redb[lane + 64];
            v += __int_as_float(__builtin_amdgcn_ds_swizzle(__float_as_int(v), 0x201F)); // xor 8
            v += __int_as_float(__builtin_amdgcn_ds_swizzle(__float_as_int(v), 0x401F)); // xor 16
            v += __int_as_float(__builtin_amdgcn_ds_bpermute((lane ^ 32) << 2,
                                                             __float_as_int(v)));
            // Dual publish: fast (plain -> local L2) + slow (sc1 -> IC).
            if (lane < 8) {
                unsigned bits = __float_as_uint(v);
                store_plain(ppf + (q << 3) + lane, bits);
                ic_store(pps + (q << 3) + lane, bits);
            }
            // Gather (skip at it=19 unless q==0: final reduce feeds only ws_omega).
            if (!last_it || q == 0) {
                float t = 0.0f;
                if (lane < 32) {
                    unsigned w;
                    for (;;) {
                        w = load_sc0(ppf + lane);     // fast: same-XCD L2
                        if (w != SENTINEL) break;
                        w = ic_load(pps + lane);      // slow: IC (proven path)
                        if (w != SENTINEL) break;
                        __builtin_amdgcn_s_sleep(1);
                    }
                    t = __uint_as_float(w);
                }
                // Fold over the 4 quarters (lanes xor 8 / xor 16 within 0-31).
                t += __int_as_float(__builtin_amdgcn_ds_swizzle(__float_as_int(t), 0x201F)); // xor 8
                t += __int_as_float(__builtin_amdgcn_ds_swizzle(__float_as_int(t), 0x401F)); // xor 16
                if (!last_it) {
                    if (lane < 8) redb[128 + lane] = t;   // totals -> LDS broadcast
                } else {
                    // it=19, q==0: omg needed only for the ws_omega write.
                    #pragma unroll
                    for (int m = 0; m < KMODES; ++m) {
                        float nm_ = __int_as_float(__builtin_amdgcn_readlane(__float_as_int(t), m));
                        float dn_ = __int_as_float(__builtin_amdgcn_readlane(__float_as_int(t), m + 4));
                        omg[m] = nm_ * __builtin_amdgcn_rcpf(dn_);
                    }
                }
            }
        }
        if (!last_it) {
            __syncthreads();   // barrier #2: totals visible to all waves
            #pragma unroll
            for (int m = 0; m < KMODES; ++m) {
                float nm_ = redb[128 + m];
                float dn_ = redb[128 + m + 4];
                omg[m] = nm_ * __builtin_amdgcn_rcpf(dn_);
            }
        }
        // it=19: no barrier #2 -- 15 waves fall through to the u_hat stores
        // while q==0's wave0 finishes its gather.
    }

    // Publish u_hat quarter (packed f16, sc1 -> IC) and omega (sc1).
    #pragma unroll
    for (int k = 0; k < KMODES; ++k) {
        unsigned* dst = ws_u + (size_t)(ch * KMODES + k) * HALF + (q << 11);
        #pragma unroll
        for (int u = 0; u < 2; ++u)
            ic_store(dst + tid + u * NTHREADS, pack_h2(Up[k][u].x, Up[k][u].y));
    }
    if (q == 0 && tid < KMODES)
        ic_store(ws_omega + ch * KMODES + tid, __float_as_uint(omg[tid]));
    asm volatile("s_waitcnt vmcnt(0)" ::: "memory");   // own stores at IC
    __syncthreads();                                   // whole block's stores at IC
    if (tid == 0)
        ic_store(ws_udone + (ch << 2) + q, 0u);        // done flag

    // ---------------- Phase 2: inverse for (b2,k2), channel ch2 ----------------
    const int g2  = bid & 63;               // (b,k) group (R13 write-merge map)
    const int c2  = bid >> 6;
    const int b2  = g2 >> 2, k2 = g2 & 3;
    const int ch2 = b2 * 4 + c2;
    const unsigned* pos = ws_u + (size_t)(ch2 * KMODES + k2) * HALF;

    // Block 0: omega_b[b,k] = mean_c omega[b,c,k] (payload-sentinel polls).
    if (bid == 0 && tid < 64) {
        int bb = tid >> 2, kk = tid & 3;
        float s = 0.f;
        #pragma unroll
        for (int cc = 0; cc < 4; ++cc) {
            const unsigned* p = ws_omega + ((bb * 4 + cc) << 2) + kk;
            unsigned w;
            for (;;) {
                w = ic_load(p);
                if (w != SENTINEL) break;
                __builtin_amdgcn_s_sleep(1);
            }
            s += __uint_as_float(w);
        }
        out[2097152 + tid] = 0.25f * s;
    }

    // Wait for the 4 producers of ch2 (wave0 lanes 0-3 only).
    if (tid < 4) {
        const unsigned* p = ws_udone + (ch2 << 2) + tid;
        for (;;) {
            unsigned w = ic_load(p);
            if (w != SENTINEL) break;
            __builtin_amdgcn_s_sleep(1);
        }
    }
    __syncthreads();   // producers done; also fences LDS A (red slabs) reuse

    // Z staging: batch 16 sc1 loads per thread (one IC latency), then compute.
    // Spectrum (verified R1): G[0]=conj(p[0]); G[j]=p[j]; G[8192]=conj(p[8191]);
    // G[16384-j]=conj(p[j]). E=(G[j]+G[j+8192])/2, D=(G[j]-G[j+8192])/2,
    // O=D*e^{+2pi i j/16384}, Z=E+iO.
    {
        unsigned wj[8], wh[8];
        #pragma unroll
        for (int uu = 0; uu < 8; ++uu) {
            int j = tid + uu * NTHREADS;
            wj[uu] = ic_load(pos + j);
            wh[uu] = ic_load(pos + (j ? (HALF - j) : (HALF - 1)));
        }
        #pragma unroll
        for (int uu = 0; uu < 8; ++uu) {
            int j = tid + uu * NTHREADS;
            v2f pj = unpack_h2(wj[uu]);
            v2f ph = unpack_h2(wh[uu]);
            float gjx = pj.x, gjy = (j == 0) ? -pj.y : pj.y;  // G[0] = conj(p[0])
            float ghx = ph.x, ghy = -ph.y;                     // conj
            float ex = 0.5f * (gjx + ghx), ey = 0.5f * (gjy + ghy);
            float dx = 0.5f * (gjx - ghx), dy = 0.5f * (gjy - ghy);
            float rev = (float)j * (1.0f / 16384.0f);
            float wr = __builtin_amdgcn_cosf(rev);
            float wi = __builtin_amdgcn_sinf(rev);    // e^{+2*pi*i*rev}
            float ox = dx * wr - dy * wi;
            float oy = dx * wi + dy * wr;
            A[pidx(j)] = make_float2(ex - oy, ey + ox);   // Z = E + i*O
        }
    }
    __syncthreads();

    // 8192-pt inverse FFT: 4 radix-8 passes + 1 radix-2 stage; bit-reversed out.
    for (int t = 0; t < 4; ++t) {
        fft_pass8<true>(A, tid, t);
        __syncthreads();
    }
    fft_last2(A, tid);
    __syncthreads();

    // Keep n in [4096,12288): m in [2048,6144). x[2m]=Re z, x[2m+1]=Im z.
    float* outp = out + (size_t)(b2 * 4 + k2) * 8192 * 4 + c2;
    for (int m = 2048 + tid; m < 6144; m += NTHREADS) {
        float2 z = A[pidx((int)bitrev13((unsigned)m))];
        int t0 = 2 * m - 4096;
        outp[(size_t)t0 * 4]       = z.x * (1.0f / 8192.0f);
        outp[(size_t)(t0 + 1) * 4] = z.y * (1.0f / 8192.0f);
    }
}

extern "C" void kernel_launch(void* const* d_in, const int* in_sizes, int n_in,
                              void* d_out, int out_size, void* d_ws, size_t ws_size,
                              hipStream_t stream)
{
    (void)in_sizes; (void)n_in; (void)out_size; (void)ws_size;
    const float* x = (const float*)d_in[0];
    float* out = (float*)d_out;

    // ws layout:
    //   [0, 8 MB)                    u_hat packed f16 (NOT memset; flag-gated)
    //   ctrl region (memset 0xFF each launch):
    //     ws_omega: 256 u32 (1 KB)   payload-sentinel omega words
    //     ws_partf: NITERS*64*32 u32 (160 KB) fast partials (L2 path)
    //     ws_parts: NITERS*64*32 u32 (160 KB) slow partials (IC path)
    //     ws_udone: 256 u32 (1 KB)   per-(ch,q) done flags
    unsigned* ws_u     = (unsigned*)d_ws;
    unsigned* ws_omega = (unsigned*)((char*)d_ws + (size_t)64 * 4 * HALF * 4);
    unsigned* ws_partf = ws_omega + 256;
    unsigned* ws_parts = ws_partf + (size_t)NITERS * 64 * 32;
    unsigned* ws_udone = ws_parts + (size_t)NITERS * 64 * 32;

    hipMemsetAsync(ws_omega, 0xFF,
                   (size_t)(256 + 2 * NITERS * 64 * 32 + 256) * 4, stream);
    vmd_fused<<<256, NTHREADS, 0, stream>>>(x, ws_u, ws_omega, ws_partf,
                                            ws_parts, ws_udone, out);
}

// Round 10
// 79.788 us; speedup vs baseline: 1.2301x; 1.0461x over previous
//
#include <hip/hip_runtime.h>

// VMD (Variational Mode Decomposition) for x: (16, 8192, 4) f32.
// B=16, C=4, T=8192, T2=16384, K=4, ALPHA=2000, TAU=0, 20 iterations.
// TAU=0 => lam == 0. Negative half stays 0 => iterate on 8192 positive bins.
//
// R26 = R25 (fused, R18 iteration-sync skeleton -- proven floor over
// R19/R20/R21/R25's L2 probes) + FOUR-STEP SHARED FORWARD FFT:
// R24 attribution: fwd FFT ~14us is computed 4x redundantly by the channel
// mates. Now block (ch,q) computes only Y_q = FFT_2048(z[4m+q]) (3 radix-8
// passes + radix-4 final, ~1/5 the work), publishes Y_q in natural order
// (16KB sc1 stores + vmcnt(0) + barrier + flag -- the handoff pattern
// proven by R23's u_hat->phase2), spins on its 3 mates' flags (sentinel
// words), batch-loads all four Y_r (64KB, fits exactly in LDS A), and
// reconstructs its quarter directly:
//   Z[j] = sum_r W_8192^{j r} Y_r[j mod 2048],  Z[8192-j] via conj(W),
// feeding the existing real-FFT untangle. Iterations + phase 2 unchanged.

#define HALF      8192
#define NH        8192        // half-size FFT length
#define NTHREADS  1024
#define KMODES    4
#define NITERS    20
#define ALPHA_F   2000.0f
#define SQH       0.70710678118654752440f
#define SENTINEL  0xFFFFFFFFu

typedef __fp16 half2_t __attribute__((ext_vector_type(2)));
typedef float  v2f     __attribute__((ext_vector_type(2)));

__device__ __forceinline__ unsigned bitrev13(unsigned x) { return __brev(x) >> 19; }
__device__ __forceinline__ unsigned bitrev11(unsigned x) { return __brev(x) >> 21; }
__device__ __forceinline__ int pidx(int i) { return i + (i >> 4); }   // LDS pad

__device__ __forceinline__ unsigned pack_h2(float a, float b) {
    half2_t h = __builtin_amdgcn_cvt_pkrtz(a, b);   // v_cvt_pkrtz_f16_f32
    return __builtin_bit_cast(unsigned, h);
}
__device__ __forceinline__ v2f unpack_h2(unsigned u) {
    half2_t h = __builtin_bit_cast(half2_t, u);
    v2f r; r.x = (float)h.x; r.y = (float)h.y; return r;
}

__device__ __forceinline__ unsigned ic_load(const unsigned* p) {
    return __hip_atomic_load(p, __ATOMIC_RELAXED, __HIP_MEMORY_SCOPE_AGENT);
}
__device__ __forceinline__ void ic_store(unsigned* p, unsigned v) {
    __hip_atomic_store(p, v, __ATOMIC_RELAXED, __HIP_MEMORY_SCOPE_AGENT);
}
__device__ __forceinline__ unsigned long long ic_load64(const unsigned long long* p) {
    return __hip_atomic_load(p, __ATOMIC_RELAXED, __HIP_MEMORY_SCOPE_AGENT);
}
__device__ __forceinline__ void ic_store64(unsigned long long* p, unsigned long long v) {
    __hip_atomic_store(p, v, __ATOMIC_RELAXED, __HIP_MEMORY_SCOPE_AGENT);
}
// Plain global store: lands in the XCD's L2 (L1 is write-through).
__device__ __forceinline__ void store_plain(unsigned* p, unsigned v) {
    asm volatile("global_store_dword %0, %1, off" :: "v"(p), "v"(v) : "memory");
}
// L1-bypass load: reads this XCD's L2 (sc0).
__device__ __forceinline__ unsigned load_sc0(const unsigned* p) {
    unsigned r;
    asm volatile("global_load_dword %0, %1, off sc0\n\t"
                 "s_waitcnt vmcnt(0)"
                 : "=v"(r) : "v"(p) : "memory");
    return r;
}

template <int CTRL>
__device__ __forceinline__ float dpp_add_step(float v) {
    int r = __builtin_amdgcn_update_dpp(0, __float_as_int(v), CTRL, 0xf, 0xf, true);
    return v + __int_as_float(r);
}
// Full-wave (64-lane) sum; result valid in lane 63.
__device__ __forceinline__ float wave64_sum(float v) {
    v = dpp_add_step<0x111>(v);   // row_shr:1
    v = dpp_add_step<0x112>(v);   // row_shr:2
    v = dpp_add_step<0x114>(v);   // row_shr:4
    v = dpp_add_step<0x118>(v);   // row_shr:8
    v = dpp_add_step<0x142>(v);   // row_bcast:15
    v = dpp_add_step<0x143>(v);   // row_bcast:31 -> lane63 = wave sum
    return v;
}

__device__ __forceinline__ float2 cmul(float2 a, float wr, float wi) {
    return make_float2(a.x * wr - a.y * wi, a.x * wi + a.y * wr);
}
__device__ __forceinline__ float2 cadd(float2 a, float2 b) {
    return make_float2(a.x + b.x, a.y + b.y);
}
__device__ __forceinline__ float2 csub(float2 a, float2 b) {
    return make_float2(a.x - b.x, a.y - b.y);
}

// One radix-8 DIF pass (three fused radix-2 stages), generic in Q and 1/(8Q).
template <bool INV>
__device__ __forceinline__ void fft_pass8_g(float2* A, int bf, int log2Q, float invL) {
    const int Q    = 1 << log2Q;
    const int j    = bf & (Q - 1);
    const int base = ((bf >> log2Q) << (log2Q + 3)) + j;

    float2 x[8];
    #pragma unroll
    for (int m = 0; m < 8; ++m) x[m] = A[pidx(base + m * Q)];

    float rev = (float)j * invL;
    float w1r = __builtin_amdgcn_cosf(rev);
    float w1i = INV ?  __builtin_amdgcn_sinf(rev)
                    : -__builtin_amdgcn_sinf(rev);
    float w2r = w1r * w1r - w1i * w1i, w2i = 2.0f * w1r * w1i;
    float w4r = w2r * w2r - w2i * w2i, w4i = 2.0f * w2r * w2i;
    float wsr, wsi;
    if (INV) { wsr = SQH * (w1r - w1i); wsi = SQH * (w1r + w1i); }
    else     { wsr = SQH * (w1r + w1i); wsi = SQH * (w1i - w1r); }
    float w1tr = INV ? -w1i : w1i,  w1ti = INV ? w1r : -w1r;
    float wstr = INV ? -wsi : wsi,  wsti = INV ? wsr : -wsr;
    float w2tr = INV ? -w2i : w2i,  w2ti = INV ? w2r : -w2r;

    float2 y0 = cadd(x[0], x[4]), y1 = cadd(x[1], x[5]);
    float2 y2 = cadd(x[2], x[6]), y3 = cadd(x[3], x[7]);
    float2 y4 = cmul(csub(x[0], x[4]), w1r, w1i);
    float2 y5 = cmul(csub(x[1], x[5]), wsr, wsi);
    float2 y6 = cmul(csub(x[2], x[6]), w1tr, w1ti);
    float2 y7 = cmul(csub(x[3], x[7]), wstr, wsti);

    float2 z0 = cadd(y0, y2), z2 = cmul(csub(y0, y2), w2r, w2i);
    float2 z1 = cadd(y1, y3), z3 = cmul(csub(y1, y3), w2tr, w2ti);
    float2 z4 = cadd(y4, y6), z6 = cmul(csub(y4, y6), w2r, w2i);
    float2 z5 = cadd(y5, y7), z7 = cmul(csub(y5, y7), w2tr, w2ti);

    A[pidx(base + 0 * Q)] = cadd(z0, z1);
    A[pidx(base + 1 * Q)] = cmul(csub(z0, z1), w4r, w4i);
    A[pidx(base + 2 * Q)] = cadd(z2, z3);
    A[pidx(base + 3 * Q)] = cmul(csub(z2, z3), w4r, w4i);
    A[pidx(base + 4 * Q)] = cadd(z4, z5);
    A[pidx(base + 5 * Q)] = cmul(csub(z4, z5), w4r, w4i);
    A[pidx(base + 6 * Q)] = cadd(z6, z7);
    A[pidx(base + 7 * Q)] = cmul(csub(z6, z7), w4r, w4i);
}
template <bool INV>
__device__ __forceinline__ void fft_pass8(float2* A, int tid, int t) {
    fft_pass8_g<INV>(A, tid, 10 - 3 * t, (float)(1 << (3 * t)) * (1.0f / 8192.0f));
}

// Final radix-2 stage for the 8192 FFT (half=1): pairs (2t,2t+1), twiddle 1.
__device__ __forceinline__ void fft_last2(float2* A, int tid) {
    #pragma unroll
    for (int u = 0; u < 4; ++u) {
        int t  = tid + u * NTHREADS;
        int i0 = 2 * t, i1 = 2 * t + 1;
        float2 a = A[pidx(i0)], b = A[pidx(i1)];
        A[pidx(i0)] = make_float2(a.x + b.x, a.y + b.y);
        A[pidx(i1)] = make_float2(a.x - b.x, a.y - b.y);
    }
}

// Final radix-4 (two fused radix-2 DIF stages, forward) for the 2048 FFT.
// Group g: indices {4g..4g+3}; output stays digit(=bit)-reversed overall.
__device__ __forceinline__ void fft2048_last4(float2* A, int g) {
    int i0 = 4 * g;
    float2 a0 = A[pidx(i0)], a1 = A[pidx(i0 + 1)];
    float2 a2 = A[pidx(i0 + 2)], a3 = A[pidx(i0 + 3)];
    float2 b0 = cadd(a0, a2), b1 = cadd(a1, a3);
    float2 b2 = csub(a0, a2);
    float2 d  = csub(a1, a3);
    float2 b3 = make_float2(d.y, -d.x);          // d * (-i), forward
    A[pidx(i0)]     = cadd(b0, b1);
    A[pidx(i0 + 1)] = csub(b0, b1);
    A[pidx(i0 + 2)] = cadd(b2, b3);
    A[pidx(i0 + 3)] = csub(b2, b3);
}

// time-domain mirror extension: f[i], i in [0,16384)
__device__ __forceinline__ int mirror_t(int i) {
    if (i < 4096)       return 4095 - i;
    else if (i < 12288) return i - 4096;
    else                return 20479 - i;
}

// ---------------------------------------------------------------------------
// Fused kernel. Grid 256, 1024 threads.
// Phase 1: bid = a*32 + 8q + r -> ch = a*8 + r, quarter q (8-apart mates).
//   Four-step FFT: compute Y_q = FFT_2048(z[4m+q]); exchange via ws_Y;
//   reconstruct quarter Z + untangle; 20 VMD iterations (R18 skeleton,
//   dual-path partials, it=19 tail skip).
// Phase 2: g = bid & 63 -> (b,k), c = bid >> 6 (R13 write-merge mapping);
//   sc1 flag handoff; batched sc1 Z staging; iFFT; scatter.
// ---------------------------------------------------------------------------
__global__ __launch_bounds__(NTHREADS) void vmd_fused(
    const float* __restrict__ x, unsigned* __restrict__ ws_u,
    unsigned* __restrict__ ws_omega, unsigned* __restrict__ ws_partf,
    unsigned* __restrict__ ws_parts, unsigned* __restrict__ ws_udone,
    unsigned* __restrict__ ws_yflag, unsigned long long* __restrict__ ws_Y,
    float* __restrict__ out)
{
    __shared__ float2 A[NH + (NH >> 4)];   // padded, ~68 KB
    const int tid = threadIdx.x;
    const int bid = blockIdx.x;
    const int r8  = bid & 7;             // XCD residue
    const int q   = (bid >> 3) & 3;      // quarter index 0..3
    const int a8  = bid >> 5;
    const int ch  = a8 * 8 + r8;         // b*4 + c
    const int b   = ch >> 2, c = ch & 3;
    const float* xb = x + (size_t)b * 8192 * 4 + c;   // x[b, t, c], stride 4

    // ---------------- Phase 1a: this block's 2048-pt sub-FFT ----------------
    // z[m] = f[2m] + i f[2m+1]; z_r[m] = z[4m+r], r == q.
    for (int m = tid; m < 2048; m += NTHREADS) {
        int i0 = 8 * m + 2 * q;
        float re = xb[(size_t)mirror_t(i0) * 4];
        float im = xb[(size_t)mirror_t(i0 + 1) * 4];
        A[pidx(m)] = make_float2(re, im);
    }
    __syncthreads();
    // 2048-pt forward FFT: 3 radix-8 passes + radix-4; bit-reversed output.
    for (int t = 0; t < 3; ++t) {
        if (tid < 256)
            fft_pass8_g<false>(A, tid, 8 - 3 * t,
                               (float)(1 << (3 * t)) * (1.0f / 2048.0f));
        __syncthreads();
    }
    if (tid < 512) fft2048_last4(A, tid);
    __syncthreads();

    // Publish Y_q in NATURAL order (sc1 -> IC), then flag (proven handoff).
    {
        unsigned long long* ydst = ws_Y + ((size_t)ch * 4 + q) * 2048;
        for (int n = tid; n < 2048; n += NTHREADS) {
            float2 v = A[pidx((int)bitrev11((unsigned)n))];
            ic_store64(ydst + n, __builtin_bit_cast(unsigned long long, v));
        }
    }
    asm volatile("s_waitcnt vmcnt(0)" ::: "memory");
    __syncthreads();
    if (tid == 0) ic_store(ws_yflag + ch * 4 + q, 0u);
    // Wait for all 4 producers of this channel (incl. self, trivially done).
    if (tid < 4) {
        const unsigned* p = ws_yflag + ch * 4 + tid;
        for (;;) {
            unsigned w = ic_load(p);
            if (w != SENTINEL) break;
            __builtin_amdgcn_s_sleep(1);
        }
    }
    __syncthreads();

    // Load all four Y_r into LDS A (natural order), 8 per thread, batched.
    {
        const unsigned long long* ysrc = ws_Y + (size_t)ch * 8192;
        unsigned long long yv[8];
        #pragma unroll
        for (int w = 0; w < 8; ++w)
            yv[w] = ic_load64(ysrc + tid + w * NTHREADS);
        #pragma unroll
        for (int w = 0; w < 8; ++w)
            A[pidx(tid + w * NTHREADS)] = __builtin_bit_cast(float2, yv[w]);
    }
    __syncthreads();

    // ---------------- Phase 1b: combine + untangle our quarter ----------------
    // Z[j] = Y0[j'] + w Y1[j'] + w^2 Y2[j'] + w^3 Y3[j'], w = e^{-2pi i j/8192},
    // j = 2048q + j'; Z[(8192-j)&8191] uses conj(w) at j2' = (2048-j')&2047.
    v2f R[2];
    #pragma unroll
    for (int u = 0; u < 2; ++u) {
        int jp  = tid + u * NTHREADS;           // j' in [0,2048)
        int j   = (q << 11) + jp;
        int j2p = (2048 - jp) & 2047;
        float2 y0 = A[pidx(jp)];
        float2 y1 = A[pidx(2048 + jp)];
        float2 y2 = A[pidx(4096 + jp)];
        float2 y3 = A[pidx(6144 + jp)];
        float2 h0 = A[pidx(j2p)];
        float2 h1 = A[pidx(2048 + j2p)];
        float2 h2 = A[pidx(4096 + j2p)];
        float2 h3 = A[pidx(6144 + j2p)];
        float rev = (float)j * (1.0f / 8192.0f);
        float wr = __builtin_amdgcn_cosf(rev);
        float wi = -__builtin_amdgcn_sinf(rev);
        float w2r = wr * wr - wi * wi, w2i = 2.0f * wr * wi;
        float w3r = w2r * wr - w2i * wi, w3i = w2r * wi + w2i * wr;
        float2 zj = y0;
        zj.x += y1.x * wr  - y1.y * wi;  zj.y += y1.x * wi  + y1.y * wr;
        zj.x += y2.x * w2r - y2.y * w2i; zj.y += y2.x * w2i + y2.y * w2r;
        zj.x += y3.x * w3r - y3.y * w3i; zj.y += y3.x * w3i + y3.y * w3r;
        float2 zh = h0;                  // conj(w) powers
        zh.x += h1.x * wr  + h1.y * wi;  zh.y += -h1.x * wi  + h1.y * wr;
        zh.x += h2.x * w2r + h2.y * w2i; zh.y += -h2.x * w2i + h2.y * w2r;
        zh.x += h3.x * w3r + h3.y * w3i; zh.y += -h3.x * w3i + h3.y * w3r;
        // Real-FFT untangle (z1 = Z[j], z2 = Z[(NH-j)&(NH-1)]).
        float ex = 0.5f * (zj.x + zh.x);
        float ey = 0.5f * (zj.y - zh.y);
        float dx = 0.5f * (zj.x - zh.x);
        float dy = 0.5f * (zj.y + zh.y);
        float rev2 = (float)j * (1.0f / 16384.0f);
        float ur = __builtin_amdgcn_cosf(rev2);
        float ui = -__builtin_amdgcn_sinf(rev2);
        R[u].x = ex + ur * dy + ui * dx;
        R[u].y = ey + ui * dy - ur * dx;
    }
    __syncthreads();   // LDS now reusable as reduction scratch

    v2f Up[KMODES][2];   // U_k in f32 registers (re, im)
    #pragma unroll
    for (int u = 0; u < 2; ++u)
        #pragma unroll
        for (int k = 0; k < KMODES; ++k) { Up[k][u].x = 0.f; Up[k][u].y = 0.f; }

    const float f0 = (float)((q << 11) + tid) * (1.0f / 16384.0f);
    float omg[KMODES] = {0.0f, 0.125f, 0.25f, 0.375f};  // 0.5*k/K

    float* red = (float*)A;   // two 144-float slabs (double-buffered by parity)
    const int lane = tid & 63, wid = tid >> 6;

    for (int it = 0; it < NITERS; ++it) {
        v2f nd[KMODES];       // (num, den) packed per mode
        #pragma unroll
        for (int k = 0; k < KMODES; ++k) { nd[k].x = 0.f; nd[k].y = 0.f; }
        #pragma unroll
        for (int u = 0; u < 2; ++u) {
            const float fru = f0 + (float)u * 0.0625f;
            v2f fv; fv.x = fru; fv.y = 1.0f;
            #pragma unroll
            for (int k = 0; k < KMODES; ++k) {
                float d   = fru - omg[k];
                float dnm = fmaf(ALPHA_F * d, d, 1.0f);
                float rcp = __builtin_amdgcn_rcpf(dnm);
                v2f uo  = Up[k][u];
                v2f nm  = R[u] + uo;          // v_pk_add_f32
                v2f un  = nm * rcp;           // v_pk_mul_f32 (splat)
                R[u]    = nm - un;            // v_pk_add_f32
                Up[k][u] = un;
                float p = fmaf(un.x, un.x, un.y * un.y);
                nd[k]   = fv * p + nd[k];     // v_pk_fma_f32
            }
        }
        // Stage 1: DPP wave sums, lane63 writes 8 partials for this wave.
        float num[KMODES], den[KMODES];
        #pragma unroll
        for (int m = 0; m < KMODES; ++m) {
            num[m] = wave64_sum(nd[m].x);
            den[m] = wave64_sum(nd[m].y);
        }
        float* redb = red + (it & 1) * 144;   // [0..127] wave partials, [128..135] totals
        if (lane == 63) {
            float4* r4 = (float4*)&redb[wid * 8];
            r4[0] = make_float4(num[0], num[1], num[2], num[3]);
            r4[1] = make_float4(den[0], den[1], den[2], den[3]);
        }
        __syncthreads();   // barrier #1: wave partials visible in LDS
        const bool last_it = (it == NITERS - 1);
        unsigned* ppf = ws_partf + (((size_t)it * 64 + ch) << 5);
        unsigned* pps = ws_parts + (((size_t)it * 64 + ch) << 5);
        if (wid == 0) {
            // Fold 16x8 wave partials -> block partial (lane l holds class l&7).
            float v = redb[lane] + redb[lane + 64];
            v += __int_as_float(__builtin_amdgcn_ds_swizzle(__float_as_int(v), 0x201F)); // xor 8
            v += __int_as_float(__builtin_amdgcn_ds_swizzle(__float_as_int(v), 0x401F)); // xor 16
            v += __int_as_float(__builtin_amdgcn_ds_bpermute((lane ^ 32) << 2,
                                                             __float_as_int(v)));
            // Dual publish: fast (plain -> local L2) + slow (sc1 -> IC).
            if (lane < 8) {
                unsigned bits = __float_as_uint(v);
                store_plain(ppf + (q << 3) + lane, bits);
                ic_store(pps + (q << 3) + lane, bits);
            }
            // Gather (skip at it=19 unless q==0: final reduce feeds only ws_omega).
            if (!last_it || q == 0) {
                float t = 0.0f;
                if (lane < 32) {
                    unsigned w;
                    for (;;) {
                        w = load_sc0(ppf + lane);     // fast: same-XCD L2
                        if (w != SENTINEL) break;
                        w = ic_load(pps + lane);      // slow: IC (proven path)
                        if (w != SENTINEL) break;
                        __builtin_amdgcn_s_sleep(1);
                    }
                    t = __uint_as_float(w);
                }
                // Fold over the 4 quarters (lanes xor 8 / xor 16 within 0-31).
                t += __int_as_float(__builtin_amdgcn_ds_swizzle(__float_as_int(t), 0x201F)); // xor 8
                t += __int_as_float(__builtin_amdgcn_ds_swizzle(__float_as_int(t), 0x401F)); // xor 16
                if (!last_it) {
                    if (lane < 8) redb[128 + lane] = t;   // totals -> LDS broadcast
                } else {
                    // it=19, q==0: omg needed only for the ws_omega write.
                    #pragma unroll
                    for (int m = 0; m < KMODES; ++m) {
                        float nm_ = __int_as_float(__builtin_amdgcn_readlane(__float_as_int(t), m));
                        float dn_ = __int_as_float(__builtin_amdgcn_readlane(__float_as_int(t), m + 4));
                        omg[m] = nm_ * __builtin_amdgcn_rcpf(dn_);
                    }
                }
            }
        }
        if (!last_it) {
            __syncthreads();   // barrier #2: totals visible to all waves
            #pragma unroll
            for (int m = 0; m < KMODES; ++m) {
                float nm_ = redb[128 + m];
                float dn_ = redb[128 + m + 4];
                omg[m] = nm_ * __builtin_amdgcn_rcpf(dn_);
            }
        }
        // it=19: no barrier #2 -- 15 waves fall through to the u_hat stores
        // while q==0's wave0 finishes its gather.
    }

    // Publish u_hat quarter (packed f16, sc1 -> IC) and omega (sc1).
    #pragma unroll
    for (int k = 0; k < KMODES; ++k) {
        unsigned* dst = ws_u + (size_t)(ch * KMODES + k) * HALF + (q << 11);
        #pragma unroll
        for (int u = 0; u < 2; ++u)
            ic_store(dst + tid + u * NTHREADS, pack_h2(Up[k][u].x, Up[k][u].y));
    }
    if (q == 0 && tid < KMODES)
        ic_store(ws_omega + ch * KMODES + tid, __float_as_uint(omg[tid]));
    asm volatile("s_waitcnt vmcnt(0)" ::: "memory");   // own stores at IC
    __syncthreads();                                   // whole block's stores at IC
    if (tid == 0)
        ic_store(ws_udone + (ch << 2) + q, 0u);        // done flag

    // ---------------- Phase 2: inverse for (b2,k2), channel ch2 ----------------
    const int g2  = bid & 63;               // (b,k) group (R13 write-merge map)
    const int c2  = bid >> 6;
    const int b2  = g2 >> 2, k2 = g2 & 3;
    const int ch2 = b2 * 4 + c2;
    const unsigned* pos = ws_u + (size_t)(ch2 * KMODES + k2) * HALF;

    // Block 0: omega_b[b,k] = mean_c omega[b,c,k] (payload-sentinel polls).
    if (bid == 0 && tid < 64) {
        int bb = tid >> 2, kk = tid & 3;
        float s = 0.f;
        #pragma unroll
        for (int cc = 0; cc < 4; ++cc) {
            const unsigned* p = ws_omega + ((bb * 4 + cc) << 2) + kk;
            unsigned w;
            for (;;) {
                w = ic_load(p);
                if (w != SENTINEL) break;
                __builtin_amdgcn_s_sleep(1);
            }
            s += __uint_as_float(w);
        }
        out[2097152 + tid] = 0.25f * s;
    }

    // Wait for the 4 producers of ch2 (wave0 lanes 0-3 only).
    if (tid < 4) {
        const unsigned* p = ws_udone + (ch2 << 2) + tid;
        for (;;) {
            unsigned w = ic_load(p);
            if (w != SENTINEL) break;
            __builtin_amdgcn_s_sleep(1);
        }
    }
    __syncthreads();   // producers done; also fences LDS A (red slabs) reuse

    // Z staging: batch 16 sc1 loads per thread (one IC latency), then compute.
    // Spectrum (verified R1): G[0]=conj(p[0]); G[j]=p[j]; G[8192]=conj(p[8191]);
    // G[16384-j]=conj(p[j]). E=(G[j]+G[j+8192])/2, D=(G[j]-G[j+8192])/2,
    // O=D*e^{+2pi i j/16384}, Z=E+iO.
    {
        unsigned wj[8], wh[8];
        #pragma unroll
        for (int uu = 0; uu < 8; ++uu) {
            int j = tid + uu * NTHREADS;
            wj[uu] = ic_load(pos + j);
            wh[uu] = ic_load(pos + (j ? (HALF - j) : (HALF - 1)));
        }
        #pragma unroll
        for (int uu = 0; uu < 8; ++uu) {
            int j = tid + uu * NTHREADS;
            v2f pj = unpack_h2(wj[uu]);
            v2f ph = unpack_h2(wh[uu]);
            float gjx = pj.x, gjy = (j == 0) ? -pj.y : pj.y;  // G[0] = conj(p[0])
            float ghx = ph.x, ghy = -ph.y;                     // conj
            float ex = 0.5f * (gjx + ghx), ey = 0.5f * (gjy + ghy);
            float dx = 0.5f * (gjx - ghx), dy = 0.5f * (gjy - ghy);
            float rev = (float)j * (1.0f / 16384.0f);
            float wr = __builtin_amdgcn_cosf(rev);
            float wi = __builtin_amdgcn_sinf(rev);    // e^{+2*pi*i*rev}
            float ox = dx * wr - dy * wi;
            float oy = dx * wi + dy * wr;
            A[pidx(j)] = make_float2(ex - oy, ey + ox);   // Z = E + i*O
        }
    }
    __syncthreads();

    // 8192-pt inverse FFT: 4 radix-8 passes + 1 radix-2 stage; bit-reversed out.
    for (int t = 0; t < 4; ++t) {
        fft_pass8<true>(A, tid, t);
        __syncthreads();
    }
    fft_last2(A, tid);
    __syncthreads();

    // Keep n in [4096,12288): m in [2048,6144). x[2m]=Re z, x[2m+1]=Im z.
    float* outp = out + (size_t)(b2 * 4 + k2) * 8192 * 4 + c2;
    for (int m = 2048 + tid; m < 6144; m += NTHREADS) {
        float2 z = A[pidx((int)bitrev13((unsigned)m))];
        int t0 = 2 * m - 4096;
        outp[(size_t)t0 * 4]       = z.x * (1.0f / 8192.0f);
        outp[(size_t)(t0 + 1) * 4] = z.y * (1.0f / 8192.0f);
    }
}

extern "C" void kernel_launch(void* const* d_in, const int* in_sizes, int n_in,
                              void* d_out, int out_size, void* d_ws, size_t ws_size,
                              hipStream_t stream)
{
    (void)in_sizes; (void)n_in; (void)out_size; (void)ws_size;
    const float* x = (const float*)d_in[0];
    float* out = (float*)d_out;

    // ws layout:
    //   [0, 8 MB)                    u_hat packed f16 (NOT memset; flag-gated)
    //   ctrl region (memset 0xFF each launch):
    //     ws_omega: 256 u32 (1 KB)   payload-sentinel omega words
    //     ws_partf: NITERS*64*32 u32 (160 KB) fast partials (L2 path)
    //     ws_parts: NITERS*64*32 u32 (160 KB) slow partials (IC path)
    //     ws_udone: 256 u32 (1 KB)   per-(ch,q) done flags
    //     ws_yflag: 256 u32 (1 KB)   per-(ch,r) Y-ready flags
    //   ws_Y: 64 ch * 4 r * 2048 float2 (4 MB) sub-FFT exchange (flag-gated)
    unsigned* ws_u     = (unsigned*)d_ws;
    unsigned* ws_omega = (unsigned*)((char*)d_ws + (size_t)64 * 4 * HALF * 4);
    unsigned* ws_partf = ws_omega + 256;
    unsigned* ws_parts = ws_partf + (size_t)NITERS * 64 * 32;
    unsigned* ws_udone = ws_parts + (size_t)NITERS * 64 * 32;
    unsigned* ws_yflag = ws_udone + 256;
    unsigned long long* ws_Y = (unsigned long long*)(ws_yflag + 256);

    hipMemsetAsync(ws_omega, 0xFF,
                   (size_t)(256 + 2 * NITERS * 64 * 32 + 256 + 256) * 4, stream);
    vmd_fused<<<256, NTHREADS, 0, stream>>>(x, ws_u, ws_omega, ws_partf,
                                            ws_parts, ws_udone, ws_yflag,
                                            ws_Y, out);
}

// Round 11
// 79.787 us; speedup vs baseline: 1.2301x; 1.0000x over previous
//
#include <hip/hip_runtime.h>

// VMD (Variational Mode Decomposition) for x: (16, 8192, 4) f32.
// B=16, C=4, T=8192, T2=16384, K=4, ALPHA=2000, TAU=0, 20 iterations.
// TAU=0 => lam == 0. Negative half stays 0 => iterate on 8192 positive bins.
//
// R27 = R26 (fused; four-step shared forward FFT; R18 iteration-sync
// skeleton = proven floor) + two deltas:
// 1) PHASE-2 WRITE-MERGE REMAP, policy-robust: out[b,k,t,c] lines need all
//    4 c-planes to fill a 64B line. R13's 64-apart c-mates are same-XCD
//    under %8-RR but DIFFERENT XCDs under fill-first dispatch (R26 hint).
//    New map: bid = a*32 + c*8 + s -> (b,k) group g2 = a*8+s, c2 = c.
//    The 4 c-mates sit at stride 8 inside one 32-block window: same XCD
//    under BOTH fill-first (bid/32) and %8-RR (bid%8) -> L2 line merge.
//    WRITE_SIZE ledger says ~4.6MB of current 24.9 is out-amplification.
// 2) OWN-Y REUSE in the exchange: stage own quarter to 2 regs before the
//    flag wait; reload only the 3 remote slots (-16KB IC reads/block).
// Everything else identical to R26.

#define HALF      8192
#define NH        8192        // half-size FFT length
#define NTHREADS  1024
#define KMODES    4
#define NITERS    20
#define ALPHA_F   2000.0f
#define SQH       0.70710678118654752440f
#define SENTINEL  0xFFFFFFFFu

typedef __fp16 half2_t __attribute__((ext_vector_type(2)));
typedef float  v2f     __attribute__((ext_vector_type(2)));

__device__ __forceinline__ unsigned bitrev13(unsigned x) { return __brev(x) >> 19; }
__device__ __forceinline__ unsigned bitrev11(unsigned x) { return __brev(x) >> 21; }
__device__ __forceinline__ int pidx(int i) { return i + (i >> 4); }   // LDS pad

__device__ __forceinline__ unsigned pack_h2(float a, float b) {
    half2_t h = __builtin_amdgcn_cvt_pkrtz(a, b);   // v_cvt_pkrtz_f16_f32
    return __builtin_bit_cast(unsigned, h);
}
__device__ __forceinline__ v2f unpack_h2(unsigned u) {
    half2_t h = __builtin_bit_cast(half2_t, u);
    v2f r; r.x = (float)h.x; r.y = (float)h.y; return r;
}

__device__ __forceinline__ unsigned ic_load(const unsigned* p) {
    return __hip_atomic_load(p, __ATOMIC_RELAXED, __HIP_MEMORY_SCOPE_AGENT);
}
__device__ __forceinline__ void ic_store(unsigned* p, unsigned v) {
    __hip_atomic_store(p, v, __ATOMIC_RELAXED, __HIP_MEMORY_SCOPE_AGENT);
}
__device__ __forceinline__ unsigned long long ic_load64(const unsigned long long* p) {
    return __hip_atomic_load(p, __ATOMIC_RELAXED, __HIP_MEMORY_SCOPE_AGENT);
}
__device__ __forceinline__ void ic_store64(unsigned long long* p, unsigned long long v) {
    __hip_atomic_store(p, v, __ATOMIC_RELAXED, __HIP_MEMORY_SCOPE_AGENT);
}
// Plain global store: lands in the XCD's L2 (L1 is write-through).
__device__ __forceinline__ void store_plain(unsigned* p, unsigned v) {
    asm volatile("global_store_dword %0, %1, off" :: "v"(p), "v"(v) : "memory");
}
// L1-bypass load: reads this XCD's L2 (sc0).
__device__ __forceinline__ unsigned load_sc0(const unsigned* p) {
    unsigned r;
    asm volatile("global_load_dword %0, %1, off sc0\n\t"
                 "s_waitcnt vmcnt(0)"
                 : "=v"(r) : "v"(p) : "memory");
    return r;
}

template <int CTRL>
__device__ __forceinline__ float dpp_add_step(float v) {
    int r = __builtin_amdgcn_update_dpp(0, __float_as_int(v), CTRL, 0xf, 0xf, true);
    return v + __int_as_float(r);
}
// Full-wave (64-lane) sum; result valid in lane 63.
__device__ __forceinline__ float wave64_sum(float v) {
    v = dpp_add_step<0x111>(v);   // row_shr:1
    v = dpp_add_step<0x112>(v);   // row_shr:2
    v = dpp_add_step<0x114>(v);   // row_shr:4
    v = dpp_add_step<0x118>(v);   // row_shr:8
    v = dpp_add_step<0x142>(v);   // row_bcast:15
    v = dpp_add_step<0x143>(v);   // row_bcast:31 -> lane63 = wave sum
    return v;
}

__device__ __forceinline__ float2 cmul(float2 a, float wr, float wi) {
    return make_float2(a.x * wr - a.y * wi, a.x * wi + a.y * wr);
}
__device__ __forceinline__ float2 cadd(float2 a, float2 b) {
    return make_float2(a.x + b.x, a.y + b.y);
}
__device__ __forceinline__ float2 csub(float2 a, float2 b) {
    return make_float2(a.x - b.x, a.y - b.y);
}

// One radix-8 DIF pass (three fused radix-2 stages), generic in Q and 1/(8Q).
template <bool INV>
__device__ __forceinline__ void fft_pass8_g(float2* A, int bf, int log2Q, float invL) {
    const int Q    = 1 << log2Q;
    const int j    = bf & (Q - 1);
    const int base = ((bf >> log2Q) << (log2Q + 3)) + j;

    float2 x[8];
    #pragma unroll
    for (int m = 0; m < 8; ++m) x[m] = A[pidx(base + m * Q)];

    float rev = (float)j * invL;
    float w1r = __builtin_amdgcn_cosf(rev);
    float w1i = INV ?  __builtin_amdgcn_sinf(rev)
                    : -__builtin_amdgcn_sinf(rev);
    float w2r = w1r * w1r - w1i * w1i, w2i = 2.0f * w1r * w1i;
    float w4r = w2r * w2r - w2i * w2i, w4i = 2.0f * w2r * w2i;
    float wsr, wsi;
    if (INV) { wsr = SQH * (w1r - w1i); wsi = SQH * (w1r + w1i); }
    else     { wsr = SQH * (w1r + w1i); wsi = SQH * (w1i - w1r); }
    float w1tr = INV ? -w1i : w1i,  w1ti = INV ? w1r : -w1r;
    float wstr = INV ? -wsi : wsi,  wsti = INV ? wsr : -wsr;
    float w2tr = INV ? -w2i : w2i,  w2ti = INV ? w2r : -w2r;

    float2 y0 = cadd(x[0], x[4]), y1 = cadd(x[1], x[5]);
    float2 y2 = cadd(x[2], x[6]), y3 = cadd(x[3], x[7]);
    float2 y4 = cmul(csub(x[0], x[4]), w1r, w1i);
    float2 y5 = cmul(csub(x[1], x[5]), wsr, wsi);
    float2 y6 = cmul(csub(x[2], x[6]), w1tr, w1ti);
    float2 y7 = cmul(csub(x[3], x[7]), wstr, wsti);

    float2 z0 = cadd(y0, y2), z2 = cmul(csub(y0, y2), w2r, w2i);
    float2 z1 = cadd(y1, y3), z3 = cmul(csub(y1, y3), w2tr, w2ti);
    float2 z4 = cadd(y4, y6), z6 = cmul(csub(y4, y6), w2r, w2i);
    float2 z5 = cadd(y5, y7), z7 = cmul(csub(y5, y7), w2tr, w2ti);

    A[pidx(base + 0 * Q)] = cadd(z0, z1);
    A[pidx(base + 1 * Q)] = cmul(csub(z0, z1), w4r, w4i);
    A[pidx(base + 2 * Q)] = cadd(z2, z3);
    A[pidx(base + 3 * Q)] = cmul(csub(z2, z3), w4r, w4i);
    A[pidx(base + 4 * Q)] = cadd(z4, z5);
    A[pidx(base + 5 * Q)] = cmul(csub(z4, z5), w4r, w4i);
    A[pidx(base + 6 * Q)] = cadd(z6, z7);
    A[pidx(base + 7 * Q)] = cmul(csub(z6, z7), w4r, w4i);
}
template <bool INV>
__device__ __forceinline__ void fft_pass8(float2* A, int tid, int t) {
    fft_pass8_g<INV>(A, tid, 10 - 3 * t, (float)(1 << (3 * t)) * (1.0f / 8192.0f));
}

// Final radix-2 stage for the 8192 FFT (half=1): pairs (2t,2t+1), twiddle 1.
__device__ __forceinline__ void fft_last2(float2* A, int tid) {
    #pragma unroll
    for (int u = 0; u < 4; ++u) {
        int t  = tid + u * NTHREADS;
        int i0 = 2 * t, i1 = 2 * t + 1;
        float2 a = A[pidx(i0)], b = A[pidx(i1)];
        A[pidx(i0)] = make_float2(a.x + b.x, a.y + b.y);
        A[pidx(i1)] = make_float2(a.x - b.x, a.y - b.y);
    }
}

// Final radix-4 (two fused radix-2 DIF stages, forward) for the 2048 FFT.
__device__ __forceinline__ void fft2048_last4(float2* A, int g) {
    int i0 = 4 * g;
    float2 a0 = A[pidx(i0)], a1 = A[pidx(i0 + 1)];
    float2 a2 = A[pidx(i0 + 2)], a3 = A[pidx(i0 + 3)];
    float2 b0 = cadd(a0, a2), b1 = cadd(a1, a3);
    float2 b2 = csub(a0, a2);
    float2 d  = csub(a1, a3);
    float2 b3 = make_float2(d.y, -d.x);          // d * (-i), forward
    A[pidx(i0)]     = cadd(b0, b1);
    A[pidx(i0 + 1)] = csub(b0, b1);
    A[pidx(i0 + 2)] = cadd(b2, b3);
    A[pidx(i0 + 3)] = csub(b2, b3);
}

// time-domain mirror extension: f[i], i in [0,16384)
__device__ __forceinline__ int mirror_t(int i) {
    if (i < 4096)       return 4095 - i;
    else if (i < 12288) return i - 4096;
    else                return 20479 - i;
}

// ---------------------------------------------------------------------------
// Fused kernel. Grid 256, 1024 threads.
// Phase 1: bid = a*32 + 8q + r -> ch = a*8 + r, quarter q (8-apart mates).
//   Four-step FFT (own-Y reuse); 20 VMD iterations (R18 skeleton).
// Phase 2: bid = a*32 + c*8 + s -> (b,k) group g2 = a*8+s, c2 = c.
//   c-mates stride 8 in one 32-block window -> same XCD both policies.
// ---------------------------------------------------------------------------
__global__ __launch_bounds__(NTHREADS) void vmd_fused(
    const float* __restrict__ x, unsigned* __restrict__ ws_u,
    unsigned* __restrict__ ws_omega, unsigned* __restrict__ ws_partf,
    unsigned* __restrict__ ws_parts, unsigned* __restrict__ ws_udone,
    unsigned* __restrict__ ws_yflag, unsigned long long* __restrict__ ws_Y,
    float* __restrict__ out)
{
    __shared__ float2 A[NH + (NH >> 4)];   // padded, ~68 KB
    const int tid = threadIdx.x;
    const int bid = blockIdx.x;
    const int r8  = bid & 7;             // XCD residue
    const int q   = (bid >> 3) & 3;      // quarter index 0..3
    const int a8  = bid >> 5;
    const int ch  = a8 * 8 + r8;         // b*4 + c
    const int b   = ch >> 2, c = ch & 3;
    const float* xb = x + (size_t)b * 8192 * 4 + c;   // x[b, t, c], stride 4

    // ---------------- Phase 1a: this block's 2048-pt sub-FFT ----------------
    // z[m] = f[2m] + i f[2m+1]; z_r[m] = z[4m+r], r == q.
    for (int m = tid; m < 2048; m += NTHREADS) {
        int i0 = 8 * m + 2 * q;
        float re = xb[(size_t)mirror_t(i0) * 4];
        float im = xb[(size_t)mirror_t(i0 + 1) * 4];
        A[pidx(m)] = make_float2(re, im);
    }
    __syncthreads();
    // 2048-pt forward FFT: 3 radix-8 passes + radix-4; bit-reversed output.
    for (int t = 0; t < 3; ++t) {
        if (tid < 256)
            fft_pass8_g<false>(A, tid, 8 - 3 * t,
                               (float)(1 << (3 * t)) * (1.0f / 2048.0f));
        __syncthreads();
    }
    if (tid < 512) fft2048_last4(A, tid);
    __syncthreads();

    // Publish Y_q in NATURAL order (sc1 -> IC), then flag (proven handoff).
    // Also stage own quarter into registers (natural order) for reuse.
    float2 own0, own1;
    {
        unsigned long long* ydst = ws_Y + ((size_t)ch * 4 + q) * 2048;
        own0 = A[pidx((int)bitrev11((unsigned)tid))];
        own1 = A[pidx((int)bitrev11((unsigned)(tid + NTHREADS)))];
        ic_store64(ydst + tid,            __builtin_bit_cast(unsigned long long, own0));
        ic_store64(ydst + tid + NTHREADS, __builtin_bit_cast(unsigned long long, own1));
    }
    asm volatile("s_waitcnt vmcnt(0)" ::: "memory");
    __syncthreads();
    if (tid == 0) ic_store(ws_yflag + ch * 4 + q, 0u);
    // Wait for the 3 remote producers of this channel.
    if (tid < 4) {
        const unsigned* p = ws_yflag + ch * 4 + tid;
        for (;;) {
            unsigned w = ic_load(p);
            if (w != SENTINEL) break;
            __builtin_amdgcn_s_sleep(1);
        }
    }
    __syncthreads();

    // Exchange: write own slot from regs; batch-load the 3 remote slots.
    {
        A[pidx((q << 11) + tid)]            = own0;
        A[pidx((q << 11) + tid + NTHREADS)] = own1;
        const unsigned long long* ysrc = ws_Y + (size_t)ch * 8192;
        unsigned long long yv[6];
        int ri[3], n = 0;
        #pragma unroll
        for (int r = 0; r < 4; ++r) if (r != q) ri[n++] = r;
        #pragma unroll
        for (int w = 0; w < 3; ++w) {
            yv[2 * w]     = ic_load64(ysrc + (ri[w] << 11) + tid);
            yv[2 * w + 1] = ic_load64(ysrc + (ri[w] << 11) + tid + NTHREADS);
        }
        #pragma unroll
        for (int w = 0; w < 3; ++w) {
            A[pidx((ri[w] << 11) + tid)]            = __builtin_bit_cast(float2, yv[2 * w]);
            A[pidx((ri[w] << 11) + tid + NTHREADS)] = __builtin_bit_cast(float2, yv[2 * w + 1]);
        }
    }
    __syncthreads();

    // ---------------- Phase 1b: combine + untangle our quarter ----------------
    // Z[j] = Y0[j'] + w Y1[j'] + w^2 Y2[j'] + w^3 Y3[j'], w = e^{-2pi i j/8192},
    // j = 2048q + j'; Z[(8192-j)&8191] uses conj(w) at j2' = (2048-j')&2047.
    v2f R[2];
    #pragma unroll
    for (int u = 0; u < 2; ++u) {
        int jp  = tid + u * NTHREADS;           // j' in [0,2048)
        int j   = (q << 11) + jp;
        int j2p = (2048 - jp) & 2047;
        float2 y0 = A[pidx(jp)];
        float2 y1 = A[pidx(2048 + jp)];
        float2 y2 = A[pidx(4096 + jp)];
        float2 y3 = A[pidx(6144 + jp)];
        float2 h0 = A[pidx(j2p)];
        float2 h1 = A[pidx(2048 + j2p)];
        float2 h2 = A[pidx(4096 + j2p)];
        float2 h3 = A[pidx(6144 + j2p)];
        float rev = (float)j * (1.0f / 8192.0f);
        float wr = __builtin_amdgcn_cosf(rev);
        float wi = -__builtin_amdgcn_sinf(rev);
        float w2r = wr * wr - wi * wi, w2i = 2.0f * wr * wi;
        float w3r = w2r * wr - w2i * wi, w3i = w2r * wi + w2i * wr;
        float2 zj = y0;
        zj.x += y1.x * wr  - y1.y * wi;  zj.y += y1.x * wi  + y1.y * wr;
        zj.x += y2.x * w2r - y2.y * w2i; zj.y += y2.x * w2i + y2.y * w2r;
        zj.x += y3.x * w3r - y3.y * w3i; zj.y += y3.x * w3i + y3.y * w3r;
        float2 zh = h0;                  // conj(w) powers
        zh.x += h1.x * wr  + h1.y * wi;  zh.y += -h1.x * wi  + h1.y * wr;
        zh.x += h2.x * w2r + h2.y * w2i; zh.y += -h2.x * w2i + h2.y * w2r;
        zh.x += h3.x * w3r + h3.y * w3i; zh.y += -h3.x * w3i + h3.y * w3r;
        // Real-FFT untangle (z1 = Z[j], z2 = Z[(NH-j)&(NH-1)]).
        float ex = 0.5f * (zj.x + zh.x);
        float ey = 0.5f * (zj.y - zh.y);
        float dx = 0.5f * (zj.x - zh.x);
        float dy = 0.5f * (zj.y + zh.y);
        float rev2 = (float)j * (1.0f / 16384.0f);
        float ur = __builtin_amdgcn_cosf(rev2);
        float ui = -__builtin_amdgcn_sinf(rev2);
        R[u].x = ex + ur * dy + ui * dx;
        R[u].y = ey + ui * dy - ur * dx;
    }
    __syncthreads();   // LDS now reusable as reduction scratch

    v2f Up[KMODES][2];   // U_k in f32 registers (re, im)
    #pragma unroll
    for (int u = 0; u < 2; ++u)
        #pragma unroll
        for (int k = 0; k < KMODES; ++k) { Up[k][u].x = 0.f; Up[k][u].y = 0.f; }

    const float f0 = (float)((q << 11) + tid) * (1.0f / 16384.0f);
    float omg[KMODES] = {0.0f, 0.125f, 0.25f, 0.375f};  // 0.5*k/K

    float* red = (float*)A;   // two 144-float slabs (double-buffered by parity)
    const int lane = tid & 63, wid = tid >> 6;

    for (int it = 0; it < NITERS; ++it) {
        v2f nd[KMODES];       // (num, den) packed per mode
        #pragma unroll
        for (int k = 0; k < KMODES; ++k) { nd[k].x = 0.f; nd[k].y = 0.f; }
        #pragma unroll
        for (int u = 0; u < 2; ++u) {
            const float fru = f0 + (float)u * 0.0625f;
            v2f fv; fv.x = fru; fv.y = 1.0f;
            #pragma unroll
            for (int k = 0; k < KMODES; ++k) {
                float d   = fru - omg[k];
                float dnm = fmaf(ALPHA_F * d, d, 1.0f);
                float rcp = __builtin_amdgcn_rcpf(dnm);
                v2f uo  = Up[k][u];
                v2f nm  = R[u] + uo;          // v_pk_add_f32
                v2f un  = nm * rcp;           // v_pk_mul_f32 (splat)
                R[u]    = nm - un;            // v_pk_add_f32
                Up[k][u] = un;
                float p = fmaf(un.x, un.x, un.y * un.y);
                nd[k]   = fv * p + nd[k];     // v_pk_fma_f32
            }
        }
        // Stage 1: DPP wave sums, lane63 writes 8 partials for this wave.
        float num[KMODES], den[KMODES];
        #pragma unroll
        for (int m = 0; m < KMODES; ++m) {
            num[m] = wave64_sum(nd[m].x);
            den[m] = wave64_sum(nd[m].y);
        }
        float* redb = red + (it & 1) * 144;   // [0..127] wave partials, [128..135] totals
        if (lane == 63) {
            float4* r4 = (float4*)&redb[wid * 8];
            r4[0] = make_float4(num[0], num[1], num[2], num[3]);
            r4[1] = make_float4(den[0], den[1], den[2], den[3]);
        }
        __syncthreads();   // barrier #1: wave partials visible in LDS
        const bool last_it = (it == NITERS - 1);
        unsigned* ppf = ws_partf + (((size_t)it * 64 + ch) << 5);
        unsigned* pps = ws_parts + (((size_t)it * 64 + ch) << 5);
        if (wid == 0) {
            // Fold 16x8 wave partials -> block partial (lane l holds class l&7).
            float v = redb[lane] + redb[lane + 64];
            v += __int_as_float(__builtin_amdgcn_ds_swizzle(__float_as_int(v), 0x201F)); // xor 8
            v += __int_as_float(__builtin_amdgcn_ds_swizzle(__float_as_int(v), 0x401F)); // xor 16
            v += __int_as_float(__builtin_amdgcn_ds_bpermute((lane ^ 32) << 2,
                                                             __float_as_int(v)));
            // Dual publish: fast (plain -> local L2) + slow (sc1 -> IC).
            if (lane < 8) {
                unsigned bits = __float_as_uint(v);
                store_plain(ppf + (q << 3) + lane, bits);
                ic_store(pps + (q << 3) + lane, bits);
            }
            // Gather (skip at it=19 unless q==0: final reduce feeds only ws_omega).
            if (!last_it || q == 0) {
                float t = 0.0f;
                if (lane < 32) {
                    unsigned w;
                    for (;;) {
                        w = load_sc0(ppf + lane);     // fast: same-XCD L2
                        if (w != SENTINEL) break;
                        w = ic_load(pps + lane);      // slow: IC (proven path)
                        if (w != SENTINEL) break;
                        __builtin_amdgcn_s_sleep(1);
                    }
                    t = __uint_as_float(w);
                }
                // Fold over the 4 quarters (lanes xor 8 / xor 16 within 0-31).
                t += __int_as_float(__builtin_amdgcn_ds_swizzle(__float_as_int(t), 0x201F)); // xor 8
                t += __int_as_float(__builtin_amdgcn_ds_swizzle(__float_as_int(t), 0x401F)); // xor 16
                if (!last_it) {
                    if (lane < 8) redb[128 + lane] = t;   // totals -> LDS broadcast
                } else {
                    // it=19, q==0: omg needed only for the ws_omega write.
                    #pragma unroll
                    for (int m = 0; m < KMODES; ++m) {
                        float nm_ = __int_as_float(__builtin_amdgcn_readlane(__float_as_int(t), m));
                        float dn_ = __int_as_float(__builtin_amdgcn_readlane(__float_as_int(t), m + 4));
                        omg[m] = nm_ * __builtin_amdgcn_rcpf(dn_);
                    }
                }
            }
        }
        if (!last_it) {
            __syncthreads();   // barrier #2: totals visible to all waves
            #pragma unroll
            for (int m = 0; m < KMODES; ++m) {
                float nm_ = redb[128 + m];
                float dn_ = redb[128 + m + 4];
                omg[m] = nm_ * __builtin_amdgcn_rcpf(dn_);
            }
        }
        // it=19: no barrier #2 -- 15 waves fall through to the u_hat stores
        // while q==0's wave0 finishes its gather.
    }

    // Publish u_hat quarter (packed f16, sc1 -> IC) and omega (sc1).
    #pragma unroll
    for (int k = 0; k < KMODES; ++k) {
        unsigned* dst = ws_u + (size_t)(ch * KMODES + k) * HALF + (q << 11);
        #pragma unroll
        for (int u = 0; u < 2; ++u)
            ic_store(dst + tid + u * NTHREADS, pack_h2(Up[k][u].x, Up[k][u].y));
    }
    if (q == 0 && tid < KMODES)
        ic_store(ws_omega + ch * KMODES + tid, __float_as_uint(omg[tid]));
    asm volatile("s_waitcnt vmcnt(0)" ::: "memory");   // own stores at IC
    __syncthreads();                                   // whole block's stores at IC
    if (tid == 0)
        ic_store(ws_udone + (ch << 2) + q, 0u);        // done flag

    // ---------------- Phase 2: inverse for (b2,k2), channel ch2 ----------------
    // Write-merge remap: bid = a*32 + c*8 + s -> g2 = a*8+s, c2 = c.
    // The 4 c-mates of a (b,k) sit at stride 8 inside one 32-block window:
    // same XCD under fill-first (bid/32) AND %8-RR (bid%8) -> L2 line merge.
    const int s2  = bid & 7;
    const int c2  = (bid >> 3) & 3;
    const int a2  = bid >> 5;
    const int g2  = a2 * 8 + s2;            // (b,k) group
    const int b2  = g2 >> 2, k2 = g2 & 3;
    const int ch2 = b2 * 4 + c2;
    const unsigned* pos = ws_u + (size_t)(ch2 * KMODES + k2) * HALF;

    // Block 0: omega_b[b,k] = mean_c omega[b,c,k] (payload-sentinel polls).
    if (bid == 0 && tid < 64) {
        int bb = tid >> 2, kk = tid & 3;
        float s = 0.f;
        #pragma unroll
        for (int cc = 0; cc < 4; ++cc) {
            const unsigned* p = ws_omega + ((bb * 4 + cc) << 2) + kk;
            unsigned w;
            for (;;) {
                w = ic_load(p);
                if (w != SENTINEL) break;
                __builtin_amdgcn_s_sleep(1);
            }
            s += __uint_as_float(w);
        }
        out[2097152 + tid] = 0.25f * s;
    }

    // Wait for the 4 producers of ch2 (wave0 lanes 0-3 only).
    if (tid < 4) {
        const unsigned* p = ws_udone + (ch2 << 2) + tid;
        for (;;) {
            unsigned w = ic_load(p);
            if (w != SENTINEL) break;
            __builtin_amdgcn_s_sleep(1);
        }
    }
    __syncthreads();   // producers done; also fences LDS A (red slabs) reuse

    // Z staging: batch 16 sc1 loads per thread (one IC latency), then compute.
    // Spectrum (verified R1): G[0]=conj(p[0]); G[j]=p[j]; G[8192]=conj(p[8191]);
    // G[16384-j]=conj(p[j]). E=(G[j]+G[j+8192])/2, D=(G[j]-G[j+8192])/2,
    // O=D*e^{+2pi i j/16384}, Z=E+iO.
    {
        unsigned wj[8], wh[8];
        #pragma unroll
        for (int uu = 0; uu < 8; ++uu) {
            int j = tid + uu * NTHREADS;
            wj[uu] = ic_load(pos + j);
            wh[uu] = ic_load(pos + (j ? (HALF - j) : (HALF - 1)));
        }
        #pragma unroll
        for (int uu = 0; uu < 8; ++uu) {
            int j = tid + uu * NTHREADS;
            v2f pj = unpack_h2(wj[uu]);
            v2f ph = unpack_h2(wh[uu]);
            float gjx = pj.x, gjy = (j == 0) ? -pj.y : pj.y;  // G[0] = conj(p[0])
            float ghx = ph.x, ghy = -ph.y;                     // conj
            float ex = 0.5f * (gjx + ghx), ey = 0.5f * (gjy + ghy);
            float dx = 0.5f * (gjx - ghx), dy = 0.5f * (gjy - ghy);
            float rev = (float)j * (1.0f / 16384.0f);
            float wr = __builtin_amdgcn_cosf(rev);
            float wi = __builtin_amdgcn_sinf(rev);    // e^{+2*pi*i*rev}
            float ox = dx * wr - dy * wi;
            float oy = dx * wi + dy * wr;
            A[pidx(j)] = make_float2(ex - oy, ey + ox);   // Z = E + i*O
        }
    }
    __syncthreads();

    // 8192-pt inverse FFT: 4 radix-8 passes + 1 radix-2 stage; bit-reversed out.
    for (int t = 0; t < 4; ++t) {
        fft_pass8<true>(A, tid, t);
        __syncthreads();
    }
    fft_last2(A, tid);
    __syncthreads();

    // Keep n in [4096,12288): m in [2048,6144). x[2m]=Re z, x[2m+1]=Im z.
    float* outp = out + (size_t)(b2 * 4 + k2) * 8192 * 4 + c2;
    for (int m = 2048 + tid; m < 6144; m += NTHREADS) {
        float2 z = A[pidx((int)bitrev13((unsigned)m))];
        int t0 = 2 * m - 4096;
        outp[(size_t)t0 * 4]       = z.x * (1.0f / 8192.0f);
        outp[(size_t)(t0 + 1) * 4] = z.y * (1.0f / 8192.0f);
    }
}

extern "C" void kernel_launch(void* const* d_in, const int* in_sizes, int n_in,
                              void* d_out, int out_size, void* d_ws, size_t ws_size,
                              hipStream_t stream)
{
    (void)in_sizes; (void)n_in; (void)out_size; (void)ws_size;
    const float* x = (const float*)d_in[0];
    float* out = (float*)d_out;

    // ws layout:
    //   [0, 8 MB)                    u_hat packed f16 (NOT memset; flag-gated)
    //   ctrl region (memset 0xFF each launch):
    //     ws_omega: 256 u32 (1 KB)   payload-sentinel omega words
    //     ws_partf: NITERS*64*32 u32 (160 KB) fast partials (L2 path)
    //     ws_parts: NITERS*64*32 u32 (160 KB) slow partials (IC path)
    //     ws_udone: 256 u32 (1 KB)   per-(ch,q) done flags
    //     ws_yflag: 256 u32 (1 KB)   per-(ch,r) Y-ready flags
    //   ws_Y: 64 ch * 4 r * 2048 float2 (4 MB) sub-FFT exchange (flag-gated)
    unsigned* ws_u     = (unsigned*)d_ws;
    unsigned* ws_omega = (unsigned*)((char*)d_ws + (size_t)64 * 4 * HALF * 4);
    unsigned* ws_partf = ws_omega + 256;
    unsigned* ws_parts = ws_partf + (size_t)NITERS * 64 * 32;
    unsigned* ws_udone = ws_parts + (size_t)NITERS * 64 * 32;
    unsigned* ws_yflag = ws_udone + 256;
    unsigned long long* ws_Y = (unsigned long long*)(ws_yflag + 256);

    hipMemsetAsync(ws_omega, 0xFF,
                   (size_t)(256 + 2 * NITERS * 64 * 32 + 256 + 256) * 4, stream);
    vmd_fused<<<256, NTHREADS, 0, stream>>>(x, ws_u, ws_omega, ws_partf,
                                            ws_parts, ws_udone, ws_yflag,
                                            ws_Y, out);
}